// Round 2
// baseline (8456.799 us; speedup 1.0000x reference)
//
#include <hip/hip_runtime.h>

#define N_NODES 100000
#define N_EDGES 3200000
// FEATURE == HIDDEN == 128
// edge_index arrives as int32 (harness converts integer inputs to int):
// ei[0..E) = src, ei[E..2E) = dst.

// ---------------- preprocessing ----------------

__global__ __launch_bounds__(256) void k_deg_init(float* __restrict__ deg) {
    int i = blockIdx.x * 256 + threadIdx.x;
    if (i < N_NODES) deg[i] = 1.0f;  // self loop
}

__global__ __launch_bounds__(256) void k_deg(const int* __restrict__ ei,
                                             float* __restrict__ deg) {
    int e = blockIdx.x * 256 + threadIdx.x;
    if (e >= N_EDGES) return;
    atomicAdd(&deg[ei[N_EDGES + e]], 1.0f);
}

__global__ __launch_bounds__(256) void k_dinv(float* __restrict__ deg) {
    int i = blockIdx.x * 256 + threadIdx.x;
    if (i < N_NODES) deg[i] = rsqrtf(deg[i]);  // deg >= 1 always
}

// ---------------- GEMM: H = X @ W  (X:[N,128], W:[128,128]) ----------------
// 16 rows per block, 1 row x 8 cols per thread. W staged in LDS in two
// 64x128 halves (32KB) to stay under the 64KB static-LDS limit.

__global__ __launch_bounds__(256) void k_gemm(const float* __restrict__ X,
                                              const float* __restrict__ W,
                                              float* __restrict__ H) {
    __shared__ float Ws[64 * 128];      // 32 KB
    __shared__ float Xs[16 * 132];      // 8.25 KB, padded to kill bank conflicts

    int t = threadIdx.x;
    long long row0 = (long long)blockIdx.x * 16;

    // load X tile: 16 rows x 128 cols = 512 float4
    const float4* X4 = (const float4*)(X + row0 * 128);
    for (int i = t; i < 512; i += 256) {
        float4 xv = X4[i];
        int r = i >> 5, c = (i & 31) << 2;
        float* p = &Xs[r * 132 + c];
        p[0] = xv.x; p[1] = xv.y; p[2] = xv.z; p[3] = xv.w;
    }

    int r  = t >> 4;            // 0..15
    int cg = (t & 15) << 3;     // col base: 0,8,...,120

    float acc[8];
#pragma unroll
    for (int i = 0; i < 8; ++i) acc[i] = 0.0f;

    for (int p = 0; p < 2; ++p) {
        __syncthreads();  // Xs ready (p=0) / Ws reuse hazard (p=1)
        const float4* W4 = (const float4*)(W + p * 64 * 128);
        for (int i = t; i < 2048; i += 256) {
            float4 wv = W4[i];
            float* q = &Ws[i << 2];
            q[0] = wv.x; q[1] = wv.y; q[2] = wv.z; q[3] = wv.w;
        }
        __syncthreads();
#pragma unroll
        for (int k = 0; k < 64; ++k) {
            float xv = Xs[r * 132 + p * 64 + k];
            const float4 w0 = *(const float4*)&Ws[k * 128 + cg];
            const float4 w1 = *(const float4*)&Ws[k * 128 + cg + 4];
            acc[0] += xv * w0.x; acc[1] += xv * w0.y;
            acc[2] += xv * w0.z; acc[3] += xv * w0.w;
            acc[4] += xv * w1.x; acc[5] += xv * w1.y;
            acc[6] += xv * w1.z; acc[7] += xv * w1.w;
        }
    }

    float* o = H + (row0 + r) * 128 + cg;
    *(float4*)o       = make_float4(acc[0], acc[1], acc[2], acc[3]);
    *(float4*)(o + 4) = make_float4(acc[4], acc[5], acc[6], acc[7]);
}

// ---------------- aggregation ----------------
// self-loop term: out[i,:] = h[i,:] * dinv[i]^2   (writes every element)
__global__ __launch_bounds__(256) void k_agg_init(const float* __restrict__ H,
                                                  const float* __restrict__ dinv,
                                                  float* __restrict__ out) {
    int j = blockIdx.x * 256 + threadIdx.x;   // float4 index, N*32 total
    int node = j >> 5;
    float di = dinv[node];
    float s = di * di;
    float4 h = ((const float4*)H)[j];
    ((float4*)out)[j] = make_float4(h.x * s, h.y * s, h.z * s, h.w * s);
}

// edge term: one wave per edge, 2 floats per lane, fp32 atomics
__global__ __launch_bounds__(256) void k_agg_edges(const float* __restrict__ H,
                                                   const int* __restrict__ ei,
                                                   const float* __restrict__ dinv,
                                                   float* __restrict__ out) {
    int wid  = (blockIdx.x * 256 + threadIdx.x) >> 6;  // edge id
    int lane = threadIdx.x & 63;
    if (wid >= N_EDGES) return;
    int s = ei[wid];
    int d = ei[N_EDGES + wid];
    float nrm = dinv[s] * dinv[d];
    float2 h = ((const float2*)(H + s * 128))[lane];
    float* o = out + d * 128 + lane * 2;
    atomicAdd(o,     h.x * nrm);
    atomicAdd(o + 1, h.y * nrm);
}

__global__ __launch_bounds__(256) void k_bias_relu(float* __restrict__ out,
                                                   const float* __restrict__ b) {
    int j = blockIdx.x * 256 + threadIdx.x;   // float4 index, N*32 total
    float4 v = ((float4*)out)[j];
    float4 bb = ((const float4*)b)[j & 31];
    v.x = fmaxf(v.x + bb.x, 0.0f);
    v.y = fmaxf(v.y + bb.y, 0.0f);
    v.z = fmaxf(v.z + bb.z, 0.0f);
    v.w = fmaxf(v.w + bb.w, 0.0f);
    ((float4*)out)[j] = v;
}

// ---------------- launch ----------------

extern "C" void kernel_launch(void* const* d_in, const int* in_sizes, int n_in,
                              void* d_out, int out_size, void* d_ws, size_t ws_size,
                              hipStream_t stream) {
    const float* x  = (const float*)d_in[0];
    const int*   ei = (const int*)d_in[1];   // int32: [0,E)=src, [E,2E)=dst
    const float* Wm[3] = {(const float*)d_in[2], (const float*)d_in[4], (const float*)d_in[6]};
    const float* bv[3] = {(const float*)d_in[3], (const float*)d_in[5], (const float*)d_in[7]};
    float* out = (float*)d_out;

    char* w = (char*)d_ws;
    float* dinv = (float*)w;                  // 0.4 MB
    float* bufA = (float*)(w + 400384);       // 51.2 MB (512B-aligned offset)

    // preprocessing: deg (with self loop) -> dinv
    k_deg_init<<<(N_NODES + 255) / 256, 256, 0, stream>>>(dinv);
    k_deg<<<N_EDGES / 256, 256, 0, stream>>>(ei, dinv);
    k_dinv<<<(N_NODES + 255) / 256, 256, 0, stream>>>(dinv);

    // 3 GCN layers; d_out doubles as the ping buffer (fully overwritten per layer)
    const float* xin = x;
    for (int l = 0; l < 3; ++l) {
        k_gemm<<<N_NODES / 16, 256, 0, stream>>>(xin, Wm[l], bufA);
        k_agg_init<<<N_NODES * 32 / 256, 256, 0, stream>>>(bufA, dinv, out);
        k_agg_edges<<<N_EDGES / 4, 256, 0, stream>>>(bufA, ei, dinv, out);
        k_bias_relu<<<N_NODES * 32 / 256, 256, 0, stream>>>(out, bv[l]);
        xin = out;
    }
}

// Round 3
// 1419.269 us; speedup vs baseline: 5.9586x; 5.9586x over previous
//
#include <hip/hip_runtime.h>

#define N_NODES 100000
#define N_EDGES 3200000
#define SCAN_BLOCKS 98   // ceil(100000 / 1024)
// FEATURE == HIDDEN == 128
// edge_index arrives as int32: ei[0..E) = src, ei[E..2E) = dst.

// ---------------- CSR build ----------------

__global__ __launch_bounds__(256) void k_zero_cnt(int* __restrict__ cnt) {
    int i = blockIdx.x * 256 + threadIdx.x;
    if (i < N_NODES) cnt[i] = 0;
}

__global__ __launch_bounds__(256) void k_count(const int* __restrict__ ei,
                                               int* __restrict__ cnt) {
    int e = blockIdx.x * 256 + threadIdx.x;
    if (e >= N_EDGES) return;
    atomicAdd(&cnt[ei[N_EDGES + e]], 1);
}

// dinv[i] = rsqrt(deg_in + 1 self loop); also zero the fill counters
__global__ __launch_bounds__(256) void k_prep(const int* __restrict__ cnt,
                                              float* __restrict__ dinv,
                                              int* __restrict__ fill) {
    int i = blockIdx.x * 256 + threadIdx.x;
    if (i < N_NODES) {
        dinv[i] = rsqrtf((float)(cnt[i] + 1));
        fill[i] = 0;
    }
}

// exclusive scan of cnt -> row_ptr, in three stages (1024 elems / block)
__global__ __launch_bounds__(256) void k_scan1(const int* __restrict__ cnt,
                                               int* __restrict__ row_ptr,
                                               int* __restrict__ blockSums) {
    __shared__ int ls[256];
    int t = threadIdx.x;
    int base = blockIdx.x * 1024 + t * 4;
    int v[4];
    int sum = 0;
#pragma unroll
    for (int i = 0; i < 4; ++i) {
        int idx = base + i;
        v[i] = (idx < N_NODES) ? cnt[idx] : 0;
        sum += v[i];
    }
    ls[t] = sum;
    __syncthreads();
    for (int off = 1; off < 256; off <<= 1) {
        int x = (t >= off) ? ls[t - off] : 0;
        __syncthreads();
        ls[t] += x;
        __syncthreads();
    }
    if (t == 255) blockSums[blockIdx.x] = ls[255];
    int run = ls[t] - sum;  // exclusive prefix within block
#pragma unroll
    for (int i = 0; i < 4; ++i) {
        int idx = base + i;
        if (idx < N_NODES) row_ptr[idx] = run;
        run += v[i];
    }
}

__global__ __launch_bounds__(128) void k_scan2(int* __restrict__ blockSums) {
    __shared__ int s[128];
    int t = threadIdx.x;
    int orig = (t < SCAN_BLOCKS) ? blockSums[t] : 0;
    s[t] = orig;
    __syncthreads();
    for (int off = 1; off < 128; off <<= 1) {
        int x = (t >= off) ? s[t - off] : 0;
        __syncthreads();
        s[t] += x;
        __syncthreads();
    }
    if (t < SCAN_BLOCKS) blockSums[t] = s[t] - orig;  // exclusive
}

__global__ __launch_bounds__(256) void k_scan3(int* __restrict__ row_ptr,
                                               const int* __restrict__ blockSums) {
    int add = blockSums[blockIdx.x];
    int base = blockIdx.x * 1024 + threadIdx.x * 4;
#pragma unroll
    for (int i = 0; i < 4; ++i) {
        int idx = base + i;
        if (idx < N_NODES) row_ptr[idx] += add;
    }
}

__global__ __launch_bounds__(256) void k_scatter(const int* __restrict__ ei,
                                                 const int* __restrict__ row_ptr,
                                                 int* __restrict__ fill,
                                                 int* __restrict__ csr_src) {
    int e = blockIdx.x * 256 + threadIdx.x;
    if (e >= N_EDGES) return;
    int s = ei[e];
    int d = ei[N_EDGES + e];
    int pos = row_ptr[d] + atomicAdd(&fill[d], 1);
    csr_src[pos] = s;
}

// ---------------- GEMM: H' = (X @ W) * dinv[row]  (prescaled) ----------------
// 16 rows per block, 1 row x 8 cols per thread. W staged in LDS in two halves.

__global__ __launch_bounds__(256) void k_gemm(const float* __restrict__ X,
                                              const float* __restrict__ W,
                                              const float* __restrict__ dinv,
                                              float* __restrict__ H) {
    __shared__ float Ws[64 * 128];      // 32 KB
    __shared__ float Xs[16 * 132];      // padded

    int t = threadIdx.x;
    long long row0 = (long long)blockIdx.x * 16;

    const float4* X4 = (const float4*)(X + row0 * 128);
    for (int i = t; i < 512; i += 256) {
        float4 xv = X4[i];
        int r = i >> 5, c = (i & 31) << 2;
        float* p = &Xs[r * 132 + c];
        p[0] = xv.x; p[1] = xv.y; p[2] = xv.z; p[3] = xv.w;
    }

    int r  = t >> 4;            // 0..15
    int cg = (t & 15) << 3;     // col base

    float acc[8];
#pragma unroll
    for (int i = 0; i < 8; ++i) acc[i] = 0.0f;

    for (int p = 0; p < 2; ++p) {
        __syncthreads();
        const float4* W4 = (const float4*)(W + p * 64 * 128);
        for (int i = t; i < 2048; i += 256) {
            float4 wv = W4[i];
            float* q = &Ws[i << 2];
            q[0] = wv.x; q[1] = wv.y; q[2] = wv.z; q[3] = wv.w;
        }
        __syncthreads();
#pragma unroll
        for (int k = 0; k < 64; ++k) {
            float xv = Xs[r * 132 + p * 64 + k];
            const float4 w0 = *(const float4*)&Ws[k * 128 + cg];
            const float4 w1 = *(const float4*)&Ws[k * 128 + cg + 4];
            acc[0] += xv * w0.x; acc[1] += xv * w0.y;
            acc[2] += xv * w0.z; acc[3] += xv * w0.w;
            acc[4] += xv * w1.x; acc[5] += xv * w1.y;
            acc[6] += xv * w1.z; acc[7] += xv * w1.w;
        }
    }

    float sc = dinv[row0 + r];
    float* o = H + (row0 + r) * 128 + cg;
    *(float4*)o       = make_float4(acc[0] * sc, acc[1] * sc, acc[2] * sc, acc[3] * sc);
    *(float4*)(o + 4) = make_float4(acc[4] * sc, acc[5] * sc, acc[6] * sc, acc[7] * sc);
}

// ---------------- gather aggregation + bias + relu ----------------
// out[d] = relu( dinv[d] * ( sum_{s in N(d)} H'[s] + H'[d] ) + b )
// one wave per node, 2 floats per lane.

__global__ __launch_bounds__(256) void k_gather(const float* __restrict__ H,
                                                const int* __restrict__ csr_src,
                                                const int* __restrict__ row_ptr,
                                                const int* __restrict__ cnt,
                                                const float* __restrict__ dinv,
                                                const float* __restrict__ b,
                                                float* __restrict__ out) {
    int node = blockIdx.x * 4 + (threadIdx.x >> 6);
    int lane = threadIdx.x & 63;
    if (node >= N_NODES) return;

    const float2* H2 = (const float2*)H;
    int start = row_ptr[node];
    int n = cnt[node];

    float2 acc = H2[node * 64 + lane];  // self-loop term (prescaled)

    int j = 0;
    for (; j + 4 <= n; j += 4) {
        int s0 = csr_src[start + j];
        int s1 = csr_src[start + j + 1];
        int s2 = csr_src[start + j + 2];
        int s3 = csr_src[start + j + 3];
        float2 h0 = H2[s0 * 64 + lane];
        float2 h1 = H2[s1 * 64 + lane];
        float2 h2 = H2[s2 * 64 + lane];
        float2 h3 = H2[s3 * 64 + lane];
        acc.x += (h0.x + h1.x) + (h2.x + h3.x);
        acc.y += (h0.y + h1.y) + (h2.y + h3.y);
    }
    for (; j < n; ++j) {
        int s = csr_src[start + j];
        float2 h = H2[s * 64 + lane];
        acc.x += h.x;
        acc.y += h.y;
    }

    float dd = dinv[node];
    float2 bb = ((const float2*)b)[lane];
    float2 v;
    v.x = fmaxf(fmaf(acc.x, dd, bb.x), 0.0f);
    v.y = fmaxf(fmaf(acc.y, dd, bb.y), 0.0f);
    ((float2*)out)[node * 64 + lane] = v;
}

// ---------------- launch ----------------

extern "C" void kernel_launch(void* const* d_in, const int* in_sizes, int n_in,
                              void* d_out, int out_size, void* d_ws, size_t ws_size,
                              hipStream_t stream) {
    const float* x  = (const float*)d_in[0];
    const int*   ei = (const int*)d_in[1];   // int32: [0,E)=src, [E,2E)=dst
    const float* Wm[3] = {(const float*)d_in[2], (const float*)d_in[4], (const float*)d_in[6]};
    const float* bv[3] = {(const float*)d_in[3], (const float*)d_in[5], (const float*)d_in[7]};
    float* out = (float*)d_out;

    char* w = (char*)d_ws;
    int*   cnt       = (int*)(w + 0);            // 0.4 MB
    int*   row_ptr   = (int*)(w + 400384);       // 0.4 MB
    int*   fill      = (int*)(w + 800768);       // 0.4 MB
    float* dinv      = (float*)(w + 1201152);    // 0.4 MB
    int*   blockSums = (int*)(w + 1601536);      // tiny
    int*   csr_src   = (int*)(w + 1602560);      // 12.8 MB
    float* bufA      = (float*)(w + 14403072);   // 51.2 MB  (total ~65.6 MB)

    // CSR build + dinv (runs every launch; identical work per call)
    k_zero_cnt<<<(N_NODES + 255) / 256, 256, 0, stream>>>(cnt);
    k_count<<<N_EDGES / 256, 256, 0, stream>>>(ei, cnt);
    k_prep<<<(N_NODES + 255) / 256, 256, 0, stream>>>(cnt, dinv, fill);
    k_scan1<<<SCAN_BLOCKS, 256, 0, stream>>>(cnt, row_ptr, blockSums);
    k_scan2<<<1, 128, 0, stream>>>(blockSums);
    k_scan3<<<SCAN_BLOCKS, 256, 0, stream>>>(row_ptr, blockSums);
    k_scatter<<<N_EDGES / 256, 256, 0, stream>>>(ei, row_ptr, fill, csr_src);

    // 3 GCN layers; d_out doubles as the ping buffer (fully overwritten per layer)
    const float* xin = x;
    for (int l = 0; l < 3; ++l) {
        k_gemm<<<N_NODES / 16, 256, 0, stream>>>(xin, Wm[l], dinv, bufA);
        k_gather<<<(N_NODES + 3) / 4, 256, 0, stream>>>(bufA, csr_src, row_ptr, cnt,
                                                        dinv, bv[l], out);
        xin = out;
    }
}

// Round 4
// 988.995 us; speedup vs baseline: 8.5509x; 1.4351x over previous
//
#include <hip/hip_runtime.h>
#include <hip/hip_fp16.h>

#define N_NODES 100000
#define N_EDGES 3200000
#define SCAN_BLOCKS 98   // ceil(100000 / 1024)
// FEATURE == HIDDEN == 128
// edge_index arrives as int32: ei[0..E) = src, ei[E..2E) = dst.

// ---------------- CSR build ----------------

__global__ __launch_bounds__(256) void k_zero_cnt(int* __restrict__ cnt) {
    int i = blockIdx.x * 256 + threadIdx.x;
    if (i < N_NODES) cnt[i] = 0;
}

__global__ __launch_bounds__(256) void k_count(const int* __restrict__ ei,
                                               int* __restrict__ cnt) {
    int e = blockIdx.x * 256 + threadIdx.x;
    if (e >= N_EDGES) return;
    atomicAdd(&cnt[ei[N_EDGES + e]], 1);
}

// dinv[i] = rsqrt(deg_in + 1 self loop); also zero the fill counters
__global__ __launch_bounds__(256) void k_prep(const int* __restrict__ cnt,
                                              float* __restrict__ dinv,
                                              int* __restrict__ fill) {
    int i = blockIdx.x * 256 + threadIdx.x;
    if (i < N_NODES) {
        dinv[i] = rsqrtf((float)(cnt[i] + 1));
        fill[i] = 0;
    }
}

// exclusive scan of cnt -> row_ptr (1024 elems / block)
__global__ __launch_bounds__(256) void k_scan1(const int* __restrict__ cnt,
                                               int* __restrict__ row_ptr,
                                               int* __restrict__ blockSums) {
    __shared__ int ls[256];
    int t = threadIdx.x;
    int base = blockIdx.x * 1024 + t * 4;
    int v[4];
    int sum = 0;
#pragma unroll
    for (int i = 0; i < 4; ++i) {
        int idx = base + i;
        v[i] = (idx < N_NODES) ? cnt[idx] : 0;
        sum += v[i];
    }
    ls[t] = sum;
    __syncthreads();
    for (int off = 1; off < 256; off <<= 1) {
        int x = (t >= off) ? ls[t - off] : 0;
        __syncthreads();
        ls[t] += x;
        __syncthreads();
    }
    if (t == 255) blockSums[blockIdx.x] = ls[255];
    int run = ls[t] - sum;  // exclusive prefix within block
#pragma unroll
    for (int i = 0; i < 4; ++i) {
        int idx = base + i;
        if (idx < N_NODES) row_ptr[idx] = run;
        run += v[i];
    }
}

__global__ __launch_bounds__(128) void k_scan2(int* __restrict__ blockSums) {
    __shared__ int s[128];
    int t = threadIdx.x;
    int orig = (t < SCAN_BLOCKS) ? blockSums[t] : 0;
    s[t] = orig;
    __syncthreads();
    for (int off = 1; off < 128; off <<= 1) {
        int x = (t >= off) ? s[t - off] : 0;
        __syncthreads();
        s[t] += x;
        __syncthreads();
    }
    if (t < SCAN_BLOCKS) blockSums[t] = s[t] - orig;  // exclusive
}

__global__ __launch_bounds__(256) void k_scan3(int* __restrict__ row_ptr,
                                               const int* __restrict__ blockSums) {
    int add = blockSums[blockIdx.x];
    int base = blockIdx.x * 1024 + threadIdx.x * 4;
#pragma unroll
    for (int i = 0; i < 4; ++i) {
        int idx = base + i;
        if (idx < N_NODES) row_ptr[idx] += add;
    }
}

__global__ __launch_bounds__(256) void k_scatter(const int* __restrict__ ei,
                                                 const int* __restrict__ row_ptr,
                                                 int* __restrict__ fill,
                                                 int* __restrict__ csr_src) {
    int e = blockIdx.x * 256 + threadIdx.x;
    if (e >= N_EDGES) return;
    int s = ei[e];
    int d = ei[N_EDGES + e];
    int pos = row_ptr[d] + atomicAdd(&fill[d], 1);
    csr_src[pos] = s;
}

// ------- GEMM: H16 = fp16( (X @ W) * dinv[row] )  -------
// 64 rows x 128 cols per block, 256 threads, 4 rows x 8 cols per thread.
// K split into two 64-halves; W half in LDS (32KB), X tile in LDS (16.6KB).

__global__ __launch_bounds__(256) void k_gemm(const float* __restrict__ X,
                                              const float* __restrict__ W,
                                              const float* __restrict__ dinv,
                                              __half* __restrict__ H16) {
    __shared__ float Ws[64 * 128];     // 32 KB, row k stride 128
    __shared__ float Xs[64 * 65];      // 16.6 KB, row r stride 65 (bank-spread)

    int t  = threadIdx.x;
    int row0 = blockIdx.x * 64;
    int cg = (t & 15) << 3;            // col base 0..120
    int rg = (t >> 4) << 2;            // row group 0..60

    float acc[4][8];
#pragma unroll
    for (int i = 0; i < 4; ++i)
#pragma unroll
        for (int j = 0; j < 8; ++j) acc[i][j] = 0.0f;

    int srow = t >> 4;                 // staging row 0..15
    int sk4  = (t & 15) << 2;          // staging k offset 0,4,..,60

    for (int p = 0; p < 2; ++p) {
        __syncthreads();   // protect previous half's reads
        // stage W half: 64 k x 128 cols = 2048 float4
        const float4* W4 = (const float4*)(W + p * 64 * 128);
        for (int i = t; i < 2048; i += 256) {
            float4 wv = W4[i];
            float* q = &Ws[i << 2];
            q[0] = wv.x; q[1] = wv.y; q[2] = wv.z; q[3] = wv.w;
        }
        // stage X tile: 64 rows x 64 k (cols p*64..), transED into Xs[row][k]
#pragma unroll
        for (int it = 0; it < 4; ++it) {
            int r = srow + (it << 4);
            int grow = row0 + r;
            if (grow >= N_NODES) grow = N_NODES - 1;
            float4 xv = *(const float4*)(X + (long long)grow * 128 + p * 64 + sk4);
            float* q = &Xs[r * 65 + sk4];
            q[0] = xv.x; q[1] = xv.y; q[2] = xv.z; q[3] = xv.w;
        }
        __syncthreads();
#pragma unroll
        for (int k = 0; k < 64; ++k) {
            const float4 w0 = *(const float4*)&Ws[k * 128 + cg];
            const float4 w1 = *(const float4*)&Ws[k * 128 + cg + 4];
            float x0 = Xs[(rg + 0) * 65 + k];
            float x1 = Xs[(rg + 1) * 65 + k];
            float x2 = Xs[(rg + 2) * 65 + k];
            float x3 = Xs[(rg + 3) * 65 + k];
            acc[0][0] += x0 * w0.x; acc[0][1] += x0 * w0.y; acc[0][2] += x0 * w0.z; acc[0][3] += x0 * w0.w;
            acc[0][4] += x0 * w1.x; acc[0][5] += x0 * w1.y; acc[0][6] += x0 * w1.z; acc[0][7] += x0 * w1.w;
            acc[1][0] += x1 * w0.x; acc[1][1] += x1 * w0.y; acc[1][2] += x1 * w0.z; acc[1][3] += x1 * w0.w;
            acc[1][4] += x1 * w1.x; acc[1][5] += x1 * w1.y; acc[1][6] += x1 * w1.z; acc[1][7] += x1 * w1.w;
            acc[2][0] += x2 * w0.x; acc[2][1] += x2 * w0.y; acc[2][2] += x2 * w0.z; acc[2][3] += x2 * w0.w;
            acc[2][4] += x2 * w1.x; acc[2][5] += x2 * w1.y; acc[2][6] += x2 * w1.z; acc[2][7] += x2 * w1.w;
            acc[3][0] += x3 * w0.x; acc[3][1] += x3 * w0.y; acc[3][2] += x3 * w0.z; acc[3][3] += x3 * w0.w;
            acc[3][4] += x3 * w1.x; acc[3][5] += x3 * w1.y; acc[3][6] += x3 * w1.z; acc[3][7] += x3 * w1.w;
        }
    }

#pragma unroll
    for (int i = 0; i < 4; ++i) {
        int grow = row0 + rg + i;
        if (grow >= N_NODES) break;
        float sc = dinv[grow];
        float4 pack;
        __half2* ph = (__half2*)&pack;
        ph[0] = __floats2half2_rn(acc[i][0] * sc, acc[i][1] * sc);
        ph[1] = __floats2half2_rn(acc[i][2] * sc, acc[i][3] * sc);
        ph[2] = __floats2half2_rn(acc[i][4] * sc, acc[i][5] * sc);
        ph[3] = __floats2half2_rn(acc[i][6] * sc, acc[i][7] * sc);
        *(float4*)(H16 + (long long)grow * 128 + cg) = pack;
    }
}

// ---------------- gather aggregation + bias + relu ----------------
// out[d] = relu( dinv[d] * ( sum_{s in N(d)} H'[s] + H'[d] ) + b )
// one wave per node, one half2 (4B) per lane; 256B per row per wave.

__global__ __launch_bounds__(256) void k_gather(const __half2* __restrict__ H2,
                                                const int* __restrict__ csr_src,
                                                const int* __restrict__ row_ptr,
                                                const int* __restrict__ cnt,
                                                const float* __restrict__ dinv,
                                                const float* __restrict__ b,
                                                float* __restrict__ out) {
    int node = blockIdx.x * 4 + (threadIdx.x >> 6);
    int lane = threadIdx.x & 63;
    if (node >= N_NODES) return;

    int start = row_ptr[node];
    int n = cnt[node];

    float2 self_ = __half22float2(H2[node * 64 + lane]);
    float accx = self_.x, accy = self_.y;

    int j = 0;
    for (; j + 8 <= n; j += 8) {
        int s[8];
#pragma unroll
        for (int u = 0; u < 8; ++u) s[u] = csr_src[start + j + u];
        float2 h[8];
#pragma unroll
        for (int u = 0; u < 8; ++u) h[u] = __half22float2(H2[s[u] * 64 + lane]);
#pragma unroll
        for (int u = 0; u < 8; ++u) { accx += h[u].x; accy += h[u].y; }
    }
    for (; j < n; ++j) {
        float2 h = __half22float2(H2[csr_src[start + j] * 64 + lane]);
        accx += h.x; accy += h.y;
    }

    float dd = dinv[node];
    float2 bb = ((const float2*)b)[lane];
    float2 v;
    v.x = fmaxf(fmaf(accx, dd, bb.x), 0.0f);
    v.y = fmaxf(fmaf(accy, dd, bb.y), 0.0f);
    ((float2*)out)[node * 64 + lane] = v;
}

// ---------------- launch ----------------

extern "C" void kernel_launch(void* const* d_in, const int* in_sizes, int n_in,
                              void* d_out, int out_size, void* d_ws, size_t ws_size,
                              hipStream_t stream) {
    const float* x  = (const float*)d_in[0];
    const int*   ei = (const int*)d_in[1];   // int32: [0,E)=src, [E,2E)=dst
    const float* Wm[3] = {(const float*)d_in[2], (const float*)d_in[4], (const float*)d_in[6]};
    const float* bv[3] = {(const float*)d_in[3], (const float*)d_in[5], (const float*)d_in[7]};
    float* out = (float*)d_out;

    char* w = (char*)d_ws;
    int*    cnt       = (int*)(w + 0);            // 0.4 MB
    int*    row_ptr   = (int*)(w + 400384);       // 0.4 MB
    int*    fill      = (int*)(w + 800768);       // 0.4 MB
    float*  dinv      = (float*)(w + 1201152);    // 0.4 MB
    int*    blockSums = (int*)(w + 1601536);      // tiny
    int*    csr_src   = (int*)(w + 1602560);      // 12.8 MB
    __half* H16       = (__half*)(w + 14403072);  // 25.6 MB  (total ~40 MB)

    // CSR build + dinv (identical work every call)
    k_zero_cnt<<<(N_NODES + 255) / 256, 256, 0, stream>>>(cnt);
    k_count<<<N_EDGES / 256, 256, 0, stream>>>(ei, cnt);
    k_prep<<<(N_NODES + 255) / 256, 256, 0, stream>>>(cnt, dinv, fill);
    k_scan1<<<SCAN_BLOCKS, 256, 0, stream>>>(cnt, row_ptr, blockSums);
    k_scan2<<<1, 128, 0, stream>>>(blockSums);
    k_scan3<<<SCAN_BLOCKS, 256, 0, stream>>>(row_ptr, blockSums);
    k_scatter<<<N_EDGES / 256, 256, 0, stream>>>(ei, row_ptr, fill, csr_src);

    // 3 GCN layers; d_out doubles as the fp32 ping buffer
    const float* xin = x;
    for (int l = 0; l < 3; ++l) {
        k_gemm<<<(N_NODES + 63) / 64, 256, 0, stream>>>(xin, Wm[l], dinv, H16);
        k_gather<<<(N_NODES + 3) / 4, 256, 0, stream>>>((const __half2*)H16, csr_src,
                                                        row_ptr, cnt, dinv, bv[l], out);
        xin = out;
    }
}

// Round 5
// 705.409 us; speedup vs baseline: 11.9885x; 1.4020x over previous
//
#include <hip/hip_runtime.h>
#include <hip/hip_fp16.h>

#define N_NODES 100000
#define N_EDGES 3200000
#define NBUCKETS 391          // ceil(100000 / 256); bucket = dst >> 8
#define CHUNK 12500           // N_EDGES / 256 blocks
// FEATURE == HIDDEN == 128
// edge_index arrives as int32: ei[0..E) = src, ei[E..2E) = dst.

// ---------------- bucketed CSR build ----------------

__global__ __launch_bounds__(512) void k_bzero(int* __restrict__ bucket_cnt) {
    int t = threadIdx.x;
    if (t < NBUCKETS) bucket_cnt[t] = 0;
}

// per-block LDS histogram of dst>>8, one global atomic per bin per block
__global__ __launch_bounds__(256) void k_bhist(const int* __restrict__ ei_dst,
                                               int* __restrict__ bucket_cnt) {
    __shared__ int h[NBUCKETS];
    int t = threadIdx.x;
    for (int i = t; i < NBUCKETS; i += 256) h[i] = 0;
    __syncthreads();
    int base = blockIdx.x * CHUNK;
    for (int i = t; i < CHUNK; i += 256)
        atomicAdd(&h[ei_dst[base + i] >> 8], 1);
    __syncthreads();
    for (int i = t; i < NBUCKETS; i += 256)
        if (h[i]) atomicAdd(&bucket_cnt[i], h[i]);
}

// exclusive scan of bucket counts -> bucket_base[0..NBUCKETS]; fill = base
__global__ __launch_bounds__(512) void k_bscan(const int* __restrict__ bucket_cnt,
                                               int* __restrict__ bucket_base,
                                               int* __restrict__ bucket_fill) {
    __shared__ int s[512];
    int t = threadIdx.x;
    int v = (t < NBUCKETS) ? bucket_cnt[t] : 0;
    s[t] = v;
    __syncthreads();
    for (int off = 1; off < 512; off <<= 1) {
        int x = (t >= off) ? s[t - off] : 0;
        __syncthreads();
        s[t] += x;
        __syncthreads();
    }
    int ex = s[t] - v;
    if (t < NBUCKETS) { bucket_base[t] = ex; bucket_fill[t] = ex; }
    if (t == NBUCKETS - 1) bucket_base[NBUCKETS] = s[t];
}

// partition edges into buckets: block-local hist -> bulk reserve -> append
// packed entry: src (17 bits) | dstlocal (8 bits) << 17
__global__ __launch_bounds__(256) void k_bscatter(const int* __restrict__ ei,
                                                  int* __restrict__ bucket_fill,
                                                  unsigned* __restrict__ bpairs) {
    __shared__ int h[NBUCKETS];
    __shared__ int basep[NBUCKETS];
    int t = threadIdx.x;
    const int* dstp = ei + N_EDGES;
    int base = blockIdx.x * CHUNK;

    for (int i = t; i < NBUCKETS; i += 256) h[i] = 0;
    __syncthreads();
    for (int i = t; i < CHUNK; i += 256)
        atomicAdd(&h[dstp[base + i] >> 8], 1);
    __syncthreads();
    for (int i = t; i < NBUCKETS; i += 256) {
        int c = h[i];
        basep[i] = c ? atomicAdd(&bucket_fill[i], c) : 0;
    }
    __syncthreads();
    for (int i = t; i < NBUCKETS; i += 256) h[i] = 0;  // reuse as rank
    __syncthreads();
    for (int i = t; i < CHUNK; i += 256) {
        int d = dstp[base + i];
        int s = ei[base + i];
        int b = d >> 8;
        int r = atomicAdd(&h[b], 1);
        bpairs[basep[b] + r] = (unsigned)s | ((unsigned)(d & 255) << 17);
    }
}

// one block per bucket: local hist + scan (row_ptr/cnt/dinv), LDS-atomic place
__global__ __launch_bounds__(256) void k_bbuild(const unsigned* __restrict__ bpairs,
                                                const int* __restrict__ bucket_base,
                                                int* __restrict__ row_ptr,
                                                int* __restrict__ cnt,
                                                float* __restrict__ dinv,
                                                int* __restrict__ csr_src) {
    __shared__ int h[256];
    __shared__ int sc[256];
    int b = blockIdx.x;
    int t = threadIdx.x;
    int e0 = bucket_base[b], e1 = bucket_base[b + 1];

    h[t] = 0;
    __syncthreads();
    for (int i = e0 + t; i < e1; i += 256)
        atomicAdd(&h[bpairs[i] >> 17], 1);
    __syncthreads();
    int v = h[t];
    sc[t] = v;
    __syncthreads();
    for (int off = 1; off < 256; off <<= 1) {
        int x = (t >= off) ? sc[t - off] : 0;
        __syncthreads();
        sc[t] += x;
        __syncthreads();
    }
    int ex = sc[t] - v;           // exclusive local prefix
    int node = b * 256 + t;
    if (node < N_NODES) {
        cnt[node] = v;
        dinv[node] = rsqrtf((float)(v + 1));
        row_ptr[node] = e0 + ex;
    }
    __syncthreads();
    h[t] = e0 + ex;               // reuse as absolute fill cursor
    __syncthreads();
    for (int i = e0 + t; i < e1; i += 256) {
        unsigned p = bpairs[i];
        int pos = atomicAdd(&h[p >> 17], 1);
        csr_src[pos] = (int)(p & 0x1FFFFu);
    }
}

// ------- GEMM: H16 = fp16( (X @ W) * dinv[row] )  -------
// 64 rows x 128 cols per block, 256 threads, 4 rows x 8 cols per thread.

__global__ __launch_bounds__(256) void k_gemm(const float* __restrict__ X,
                                              const float* __restrict__ W,
                                              const float* __restrict__ dinv,
                                              __half* __restrict__ H16) {
    __shared__ float Ws[64 * 128];     // 32 KB
    __shared__ float Xs[64 * 65];      // 16.6 KB, bank-spread

    int t  = threadIdx.x;
    int row0 = blockIdx.x * 64;
    int cg = (t & 15) << 3;            // col base 0..120
    int rg = (t >> 4) << 2;            // row group 0..60

    float acc[4][8];
#pragma unroll
    for (int i = 0; i < 4; ++i)
#pragma unroll
        for (int j = 0; j < 8; ++j) acc[i][j] = 0.0f;

    int srow = t >> 4;                 // staging row 0..15
    int sk4  = (t & 15) << 2;          // staging k offset 0,4,..,60

    for (int p = 0; p < 2; ++p) {
        __syncthreads();
        const float4* W4 = (const float4*)(W + p * 64 * 128);
        for (int i = t; i < 2048; i += 256) {
            float4 wv = W4[i];
            float* q = &Ws[i << 2];
            q[0] = wv.x; q[1] = wv.y; q[2] = wv.z; q[3] = wv.w;
        }
#pragma unroll
        for (int it = 0; it < 4; ++it) {
            int r = srow + (it << 4);
            int grow = row0 + r;
            if (grow >= N_NODES) grow = N_NODES - 1;
            float4 xv = *(const float4*)(X + (long long)grow * 128 + p * 64 + sk4);
            float* q = &Xs[r * 65 + sk4];
            q[0] = xv.x; q[1] = xv.y; q[2] = xv.z; q[3] = xv.w;
        }
        __syncthreads();
#pragma unroll
        for (int k = 0; k < 64; ++k) {
            const float4 w0 = *(const float4*)&Ws[k * 128 + cg];
            const float4 w1 = *(const float4*)&Ws[k * 128 + cg + 4];
            float x0 = Xs[(rg + 0) * 65 + k];
            float x1 = Xs[(rg + 1) * 65 + k];
            float x2 = Xs[(rg + 2) * 65 + k];
            float x3 = Xs[(rg + 3) * 65 + k];
            acc[0][0] += x0 * w0.x; acc[0][1] += x0 * w0.y; acc[0][2] += x0 * w0.z; acc[0][3] += x0 * w0.w;
            acc[0][4] += x0 * w1.x; acc[0][5] += x0 * w1.y; acc[0][6] += x0 * w1.z; acc[0][7] += x0 * w1.w;
            acc[1][0] += x1 * w0.x; acc[1][1] += x1 * w0.y; acc[1][2] += x1 * w0.z; acc[1][3] += x1 * w0.w;
            acc[1][4] += x1 * w1.x; acc[1][5] += x1 * w1.y; acc[1][6] += x1 * w1.z; acc[1][7] += x1 * w1.w;
            acc[2][0] += x2 * w0.x; acc[2][1] += x2 * w0.y; acc[2][2] += x2 * w0.z; acc[2][3] += x2 * w0.w;
            acc[2][4] += x2 * w1.x; acc[2][5] += x2 * w1.y; acc[2][6] += x2 * w1.z; acc[2][7] += x2 * w1.w;
            acc[3][0] += x3 * w0.x; acc[3][1] += x3 * w0.y; acc[3][2] += x3 * w0.z; acc[3][3] += x3 * w0.w;
            acc[3][4] += x3 * w1.x; acc[3][5] += x3 * w1.y; acc[3][6] += x3 * w1.z; acc[3][7] += x3 * w1.w;
        }
    }

#pragma unroll
    for (int i = 0; i < 4; ++i) {
        int grow = row0 + rg + i;
        if (grow >= N_NODES) break;
        float sc = dinv[grow];
        float4 pack;
        __half2* ph = (__half2*)&pack;
        ph[0] = __floats2half2_rn(acc[i][0] * sc, acc[i][1] * sc);
        ph[1] = __floats2half2_rn(acc[i][2] * sc, acc[i][3] * sc);
        ph[2] = __floats2half2_rn(acc[i][4] * sc, acc[i][5] * sc);
        ph[3] = __floats2half2_rn(acc[i][6] * sc, acc[i][7] * sc);
        *(float4*)(H16 + (long long)grow * 128 + cg) = pack;
    }
}

// ---------------- gather aggregation + bias + relu ----------------

__global__ __launch_bounds__(256) void k_gather(const __half2* __restrict__ H2,
                                                const int* __restrict__ csr_src,
                                                const int* __restrict__ row_ptr,
                                                const int* __restrict__ cnt,
                                                const float* __restrict__ dinv,
                                                const float* __restrict__ b,
                                                float* __restrict__ out) {
    int node = blockIdx.x * 4 + (threadIdx.x >> 6);
    int lane = threadIdx.x & 63;
    if (node >= N_NODES) return;

    int start = row_ptr[node];
    int n = cnt[node];

    float2 self_ = __half22float2(H2[node * 64 + lane]);
    float accx = self_.x, accy = self_.y;

    int j = 0;
    for (; j + 8 <= n; j += 8) {
        int s[8];
#pragma unroll
        for (int u = 0; u < 8; ++u) s[u] = csr_src[start + j + u];
        float2 h[8];
#pragma unroll
        for (int u = 0; u < 8; ++u) h[u] = __half22float2(H2[s[u] * 64 + lane]);
#pragma unroll
        for (int u = 0; u < 8; ++u) { accx += h[u].x; accy += h[u].y; }
    }
    for (; j < n; ++j) {
        float2 h = __half22float2(H2[csr_src[start + j] * 64 + lane]);
        accx += h.x; accy += h.y;
    }

    float dd = dinv[node];
    float2 bb = ((const float2*)b)[lane];
    float2 v;
    v.x = fmaxf(fmaf(accx, dd, bb.x), 0.0f);
    v.y = fmaxf(fmaf(accy, dd, bb.y), 0.0f);
    ((float2*)out)[node * 64 + lane] = v;
}

// ---------------- launch ----------------

extern "C" void kernel_launch(void* const* d_in, const int* in_sizes, int n_in,
                              void* d_out, int out_size, void* d_ws, size_t ws_size,
                              hipStream_t stream) {
    const float* x  = (const float*)d_in[0];
    const int*   ei = (const int*)d_in[1];   // int32: [0,E)=src, [E,2E)=dst
    const float* Wm[3] = {(const float*)d_in[2], (const float*)d_in[4], (const float*)d_in[6]};
    const float* bv[3] = {(const float*)d_in[3], (const float*)d_in[5], (const float*)d_in[7]};
    float* out = (float*)d_out;

    char* w = (char*)d_ws;
    int*      row_ptr     = (int*)(w + 0);            // 0.4 MB
    int*      cnt         = (int*)(w + 400384);       // 0.4 MB
    float*    dinv        = (float*)(w + 800768);     // 0.4 MB
    int*      bucket_cnt  = (int*)(w + 1201152);      // 2 KB
    int*      bucket_base = (int*)(w + 1203200);      // 2 KB (NBUCKETS+1)
    int*      bucket_fill = (int*)(w + 1205248);      // 2 KB
    unsigned* bpairs      = (unsigned*)(w + 1207296); // 12.8 MB
    int*      csr_src     = (int*)(w + 14007808);     // 12.8 MB
    __half*   H16         = (__half*)(w + 26808320);  // 25.6 MB (total ~52.4 MB)

    // CSR build via bucketed counting sort (identical work every call)
    k_bzero<<<1, 512, 0, stream>>>(bucket_cnt);
    k_bhist<<<256, 256, 0, stream>>>(ei + N_EDGES, bucket_cnt);
    k_bscan<<<1, 512, 0, stream>>>(bucket_cnt, bucket_base, bucket_fill);
    k_bscatter<<<256, 256, 0, stream>>>(ei, bucket_fill, bpairs);
    k_bbuild<<<NBUCKETS, 256, 0, stream>>>(bpairs, bucket_base, row_ptr, cnt, dinv, csr_src);

    // 3 GCN layers; d_out doubles as the fp32 ping buffer
    const float* xin = x;
    for (int l = 0; l < 3; ++l) {
        k_gemm<<<(N_NODES + 63) / 64, 256, 0, stream>>>(xin, Wm[l], dinv, H16);
        k_gather<<<(N_NODES + 3) / 4, 256, 0, stream>>>((const __half2*)H16, csr_src,
                                                        row_ptr, cnt, dinv, bv[l], out);
        xin = out;
    }
}

// Round 6
// 650.560 us; speedup vs baseline: 12.9993x; 1.0843x over previous
//
#include <hip/hip_runtime.h>
#include <hip/hip_fp16.h>

#define N_NODES 100000
#define N_EDGES 3200000
#define NBUCKETS 391          // ceil(100000 / 256); bucket = dst >> 8
#define CHUNK 12500           // N_EDGES / 256 blocks
// FEATURE == HIDDEN == 128
// edge_index arrives as int32: ei[0..E) = src, ei[E..2E) = dst.

typedef __attribute__((ext_vector_type(8))) short sh8;   // 8 bf16 (4 VGPRs)
typedef __attribute__((ext_vector_type(4))) float fl4;   // MFMA acc

// split fp32 into bf16 hi + bf16 lo (both round-to-nearest-even)
__device__ inline void split_bf16(float x, short& hi, short& lo) {
    unsigned u = __float_as_uint(x);
    unsigned r = u + 0x7FFFu + ((u >> 16) & 1u);
    hi = (short)(r >> 16);
    float hif = __uint_as_float(r & 0xFFFF0000u);
    float lof = x - hif;
    unsigned u2 = __float_as_uint(lof);
    lo = (short)((u2 + 0x7FFFu + ((u2 >> 16) & 1u)) >> 16);
}

// ---------------- bucketed CSR build ----------------

__global__ __launch_bounds__(512) void k_bzero(int* __restrict__ bucket_cnt) {
    int t = threadIdx.x;
    if (t < NBUCKETS) bucket_cnt[t] = 0;
}

__global__ __launch_bounds__(256) void k_bhist(const int* __restrict__ ei_dst,
                                               int* __restrict__ bucket_cnt) {
    __shared__ int h[NBUCKETS];
    int t = threadIdx.x;
    for (int i = t; i < NBUCKETS; i += 256) h[i] = 0;
    __syncthreads();
    int base = blockIdx.x * CHUNK;
    for (int i = t; i < CHUNK; i += 256)
        atomicAdd(&h[ei_dst[base + i] >> 8], 1);
    __syncthreads();
    for (int i = t; i < NBUCKETS; i += 256)
        if (h[i]) atomicAdd(&bucket_cnt[i], h[i]);
}

__global__ __launch_bounds__(512) void k_bscan(const int* __restrict__ bucket_cnt,
                                               int* __restrict__ bucket_base,
                                               int* __restrict__ bucket_fill) {
    __shared__ int s[512];
    int t = threadIdx.x;
    int v = (t < NBUCKETS) ? bucket_cnt[t] : 0;
    s[t] = v;
    __syncthreads();
    for (int off = 1; off < 512; off <<= 1) {
        int x = (t >= off) ? s[t - off] : 0;
        __syncthreads();
        s[t] += x;
        __syncthreads();
    }
    int ex = s[t] - v;
    if (t < NBUCKETS) { bucket_base[t] = ex; bucket_fill[t] = ex; }
    if (t == NBUCKETS - 1) bucket_base[NBUCKETS] = s[t];
}

// packed entry: src (17 bits) | dstlocal (8 bits) << 17
__global__ __launch_bounds__(256) void k_bscatter(const int* __restrict__ ei,
                                                  int* __restrict__ bucket_fill,
                                                  unsigned* __restrict__ bpairs) {
    __shared__ int h[NBUCKETS];
    __shared__ int basep[NBUCKETS];
    int t = threadIdx.x;
    const int* dstp = ei + N_EDGES;
    int base = blockIdx.x * CHUNK;

    for (int i = t; i < NBUCKETS; i += 256) h[i] = 0;
    __syncthreads();
    for (int i = t; i < CHUNK; i += 256)
        atomicAdd(&h[dstp[base + i] >> 8], 1);
    __syncthreads();
    for (int i = t; i < NBUCKETS; i += 256) {
        int c = h[i];
        basep[i] = c ? atomicAdd(&bucket_fill[i], c) : 0;
    }
    __syncthreads();
    for (int i = t; i < NBUCKETS; i += 256) h[i] = 0;  // reuse as rank
    __syncthreads();
    for (int i = t; i < CHUNK; i += 256) {
        int d = dstp[base + i];
        int s = ei[base + i];
        int b = d >> 8;
        int r = atomicAdd(&h[b], 1);
        bpairs[basep[b] + r] = (unsigned)s | ((unsigned)(d & 255) << 17);
    }
}

__global__ __launch_bounds__(256) void k_bbuild(const unsigned* __restrict__ bpairs,
                                                const int* __restrict__ bucket_base,
                                                int* __restrict__ row_ptr,
                                                int* __restrict__ cnt,
                                                float* __restrict__ dinv,
                                                int* __restrict__ csr_src) {
    __shared__ int h[256];
    __shared__ int sc[256];
    int b = blockIdx.x;
    int t = threadIdx.x;
    int e0 = bucket_base[b], e1 = bucket_base[b + 1];

    h[t] = 0;
    __syncthreads();
    for (int i = e0 + t; i < e1; i += 256)
        atomicAdd(&h[bpairs[i] >> 17], 1);
    __syncthreads();
    int v = h[t];
    sc[t] = v;
    __syncthreads();
    for (int off = 1; off < 256; off <<= 1) {
        int x = (t >= off) ? sc[t - off] : 0;
        __syncthreads();
        sc[t] += x;
        __syncthreads();
    }
    int ex = sc[t] - v;
    int node = b * 256 + t;
    if (node < N_NODES) {
        cnt[node] = v;
        dinv[node] = rsqrtf((float)(v + 1));
        row_ptr[node] = e0 + ex;
    }
    __syncthreads();
    h[t] = e0 + ex;               // absolute fill cursor
    __syncthreads();
    for (int i = e0 + t; i < e1; i += 256) {
        unsigned p = bpairs[i];
        int pos = atomicAdd(&h[p >> 17], 1);
        csr_src[pos] = (int)(p & 0x1FFFFu);
    }
}

// ------- W repack: fp32 [128x128] -> bf16 hi/lo in MFMA B-fragment order -------
// B-frag (16x16x32): lane = q*16 + n16 holds B[k = ks*32 + q*8 + j][n = c*16 + n16],
// j = 0..7 contiguous. Storage: frag[((l*32 + ks*8 + c)*64 + lane)*8 + j].

__global__ __launch_bounds__(256) void k_wprep(const float* __restrict__ W0,
                                               const float* __restrict__ W1,
                                               const float* __restrict__ W2,
                                               short* __restrict__ fhi,
                                               short* __restrict__ flo) {
    int idx = blockIdx.x * 256 + threadIdx.x;   // 3 * 16384
    int l = idx >> 14, e = idx & 16383;
    const float* W = (l == 0) ? W0 : (l == 1) ? W1 : W2;
    float w = W[e];
    int k = e >> 7, n = e & 127;
    int ks = k >> 5, q = (k >> 3) & 3, j = k & 7;
    int c = n >> 4, n16 = n & 15;
    int lane = q * 16 + n16;
    int dst = ((l * 32 + ks * 8 + c) * 64 + lane) * 8 + j;
    short hi, lo;
    split_bf16(w, hi, lo);
    fhi[dst] = hi;
    flo[dst] = lo;
}

// ------- GEMM: H16 = fp16( (X @ W) * dinv[row] ) via split-bf16 MFMA -------
// block = 256 thr (4 waves), M-tile 128; wave owns 32 rows = 2 row-tiles of 16.
// 3 passes: hi*hi + lo*hi + hi*lo (lo*lo ~1e-5 rel, dropped).

__global__ __launch_bounds__(256) void k_gemm_mfma(const float* __restrict__ X,
                                                   const short* __restrict__ fhi,
                                                   const short* __restrict__ flo,
                                                   const float* __restrict__ dinv,
                                                   __half* __restrict__ H16,
                                                   int layer) {
    int t = threadIdx.x;
    int wave = t >> 6, lane = t & 63;
    int q = lane >> 4, n16 = lane & 15;
    int row_base = blockIdx.x * 128 + wave * 32;

    const sh8* __restrict__ BH = (const sh8*)(fhi + layer * 16384);
    const sh8* __restrict__ BL = (const sh8*)(flo + layer * 16384);

    fl4 acc[2][8];
#pragma unroll
    for (int r = 0; r < 2; ++r)
#pragma unroll
        for (int c = 0; c < 8; ++c) acc[r][c] = (fl4){0.f, 0.f, 0.f, 0.f};

    long long arow[2];
    {
        int r0 = row_base + n16;       if (r0 > N_NODES - 1) r0 = N_NODES - 1;
        int r1 = row_base + 16 + n16;  if (r1 > N_NODES - 1) r1 = N_NODES - 1;
        arow[0] = r0; arow[1] = r1;
    }

#pragma unroll
    for (int ks = 0; ks < 4; ++ks) {
        sh8 ah[2], al[2];
#pragma unroll
        for (int r = 0; r < 2; ++r) {
            const float* px = X + arow[r] * 128 + ks * 32 + q * 8;
            float4 x0 = *(const float4*)px;
            float4 x1 = *(const float4*)(px + 4);
            float xs[8] = {x0.x, x0.y, x0.z, x0.w, x1.x, x1.y, x1.z, x1.w};
#pragma unroll
            for (int j = 0; j < 8; ++j) {
                short h, l;
                split_bf16(xs[j], h, l);
                ah[r][j] = h;
                al[r][j] = l;
            }
        }
#pragma unroll
        for (int c = 0; c < 8; ++c) {
            sh8 bh = BH[(ks * 8 + c) * 64 + lane];
            sh8 bl = BL[(ks * 8 + c) * 64 + lane];
#pragma unroll
            for (int r = 0; r < 2; ++r) {
                acc[r][c] = __builtin_amdgcn_mfma_f32_16x16x32_bf16(ah[r], bh, acc[r][c], 0, 0, 0);
                acc[r][c] = __builtin_amdgcn_mfma_f32_16x16x32_bf16(al[r], bh, acc[r][c], 0, 0, 0);
                acc[r][c] = __builtin_amdgcn_mfma_f32_16x16x32_bf16(ah[r], bl, acc[r][c], 0, 0, 0);
            }
        }
    }

    // epilogue: C/D layout row = q*4 + reg, col = c*16 + n16
#pragma unroll
    for (int r = 0; r < 2; ++r)
#pragma unroll
        for (int reg = 0; reg < 4; ++reg) {
            int grow = row_base + r * 16 + q * 4 + reg;
            if (grow < N_NODES) {
                float sc = dinv[grow];
                __half* dst = H16 + (long long)grow * 128 + n16;
#pragma unroll
                for (int c = 0; c < 8; ++c)
                    dst[c * 16] = __float2half(acc[r][c][reg] * sc);
            }
        }
}

// ---------------- gather aggregation + bias + relu ----------------

__global__ __launch_bounds__(256) void k_gather(const __half2* __restrict__ H2,
                                                const int* __restrict__ csr_src,
                                                const int* __restrict__ row_ptr,
                                                const int* __restrict__ cnt,
                                                const float* __restrict__ dinv,
                                                const float* __restrict__ b,
                                                float* __restrict__ out) {
    int node = blockIdx.x * 4 + (threadIdx.x >> 6);
    int lane = threadIdx.x & 63;
    if (node >= N_NODES) return;

    int start = row_ptr[node];
    int n = cnt[node];

    float2 self_ = __half22float2(H2[node * 64 + lane]);
    float accx = self_.x, accy = self_.y;

    int j = 0;
    for (; j + 8 <= n; j += 8) {
        int s[8];
#pragma unroll
        for (int u = 0; u < 8; ++u) s[u] = csr_src[start + j + u];
        float2 h[8];
#pragma unroll
        for (int u = 0; u < 8; ++u) h[u] = __half22float2(H2[s[u] * 64 + lane]);
#pragma unroll
        for (int u = 0; u < 8; ++u) { accx += h[u].x; accy += h[u].y; }
    }
    for (; j < n; ++j) {
        float2 h = __half22float2(H2[csr_src[start + j] * 64 + lane]);
        accx += h.x; accy += h.y;
    }

    float dd = dinv[node];
    float2 bb = ((const float2*)b)[lane];
    float2 v;
    v.x = fmaxf(fmaf(accx, dd, bb.x), 0.0f);
    v.y = fmaxf(fmaf(accy, dd, bb.y), 0.0f);
    ((float2*)out)[node * 64 + lane] = v;
}

// ---------------- launch ----------------

extern "C" void kernel_launch(void* const* d_in, const int* in_sizes, int n_in,
                              void* d_out, int out_size, void* d_ws, size_t ws_size,
                              hipStream_t stream) {
    const float* x  = (const float*)d_in[0];
    const int*   ei = (const int*)d_in[1];   // int32: [0,E)=src, [E,2E)=dst
    const float* Wm[3] = {(const float*)d_in[2], (const float*)d_in[4], (const float*)d_in[6]};
    const float* bv[3] = {(const float*)d_in[3], (const float*)d_in[5], (const float*)d_in[7]};
    float* out = (float*)d_out;

    char* w = (char*)d_ws;
    int*      row_ptr     = (int*)(w + 0);            // 0.4 MB
    int*      cnt         = (int*)(w + 400384);       // 0.4 MB
    float*    dinv        = (float*)(w + 800768);     // 0.4 MB
    int*      bucket_cnt  = (int*)(w + 1201152);      // 2 KB
    int*      bucket_base = (int*)(w + 1203200);      // 2 KB
    int*      bucket_fill = (int*)(w + 1205248);      // 2 KB
    unsigned* bpairs      = (unsigned*)(w + 1207296); // 12.8 MB
    int*      csr_src     = (int*)(w + 14007808);     // 12.8 MB
    short*    fragHi      = (short*)(w + 26808320);   // 96 KB (3 layers)
    short*    fragLo      = (short*)(w + 26906624);   // 96 KB
    __half*   H16         = (__half*)(w + 27004928);  // 25.6 MB (total ~52.6 MB)

    // CSR build via bucketed counting sort + W fragment repack
    k_bzero<<<1, 512, 0, stream>>>(bucket_cnt);
    k_bhist<<<256, 256, 0, stream>>>(ei + N_EDGES, bucket_cnt);
    k_bscan<<<1, 512, 0, stream>>>(bucket_cnt, bucket_base, bucket_fill);
    k_bscatter<<<256, 256, 0, stream>>>(ei, bucket_fill, bpairs);
    k_bbuild<<<NBUCKETS, 256, 0, stream>>>(bpairs, bucket_base, row_ptr, cnt, dinv, csr_src);
    k_wprep<<<192, 256, 0, stream>>>(Wm[0], Wm[1], Wm[2], fragHi, fragLo);

    // 3 GCN layers; d_out doubles as the fp32 ping buffer
    const float* xin = x;
    for (int l = 0; l < 3; ++l) {
        k_gemm_mfma<<<(N_NODES + 127) / 128, 256, 0, stream>>>(xin, fragHi, fragLo,
                                                               dinv, H16, l);
        k_gather<<<(N_NODES + 3) / 4, 256, 0, stream>>>((const __half2*)H16, csr_src,
                                                        row_ptr, cnt, dinv, bv[l], out);
        xin = out;
    }
}

// Round 7
// 625.801 us; speedup vs baseline: 13.5136x; 1.0396x over previous
//
#include <hip/hip_runtime.h>
#include <hip/hip_fp16.h>

#define N_NODES 100000
#define N_EDGES 3200000
#define NBUCKETS 391          // ceil(100000 / 256); bucket = dst >> 8
#define CHUNK 12500           // N_EDGES / 256 blocks
// FEATURE == HIDDEN == 128
// edge_index arrives as int32: ei[0..E) = src, ei[E..2E) = dst.

typedef __attribute__((ext_vector_type(8))) short sh8;   // 8 bf16 (4 VGPRs)
typedef __attribute__((ext_vector_type(4))) float fl4;   // MFMA acc

// split fp32 into bf16 hi + bf16 lo (both round-to-nearest-even)
__device__ inline void split_bf16(float x, short& hi, short& lo) {
    unsigned u = __float_as_uint(x);
    unsigned r = u + 0x7FFFu + ((u >> 16) & 1u);
    hi = (short)(r >> 16);
    float hif = __uint_as_float(r & 0xFFFF0000u);
    float lof = x - hif;
    unsigned u2 = __float_as_uint(lof);
    lo = (short)((u2 + 0x7FFFu + ((u2 >> 16) & 1u)) >> 16);
}

// ---------------- bucketed CSR build ----------------

__global__ __launch_bounds__(512) void k_bzero(int* __restrict__ bucket_cnt) {
    int t = threadIdx.x;
    if (t < NBUCKETS) bucket_cnt[t] = 0;
}

__global__ __launch_bounds__(256) void k_bhist(const int* __restrict__ ei_dst,
                                               int* __restrict__ bucket_cnt) {
    __shared__ int h[NBUCKETS];
    int t = threadIdx.x;
    for (int i = t; i < NBUCKETS; i += 256) h[i] = 0;
    __syncthreads();
    int base = blockIdx.x * CHUNK;
    for (int i = t; i < CHUNK; i += 256)
        atomicAdd(&h[ei_dst[base + i] >> 8], 1);
    __syncthreads();
    for (int i = t; i < NBUCKETS; i += 256)
        if (h[i]) atomicAdd(&bucket_cnt[i], h[i]);
}

__global__ __launch_bounds__(512) void k_bscan(const int* __restrict__ bucket_cnt,
                                               int* __restrict__ bucket_base,
                                               int* __restrict__ bucket_fill) {
    __shared__ int s[512];
    int t = threadIdx.x;
    int v = (t < NBUCKETS) ? bucket_cnt[t] : 0;
    s[t] = v;
    __syncthreads();
    for (int off = 1; off < 512; off <<= 1) {
        int x = (t >= off) ? s[t - off] : 0;
        __syncthreads();
        s[t] += x;
        __syncthreads();
    }
    int ex = s[t] - v;
    if (t < NBUCKETS) { bucket_base[t] = ex; bucket_fill[t] = ex; }
    if (t == NBUCKETS - 1) bucket_base[NBUCKETS] = s[t];
}

// packed entry: src (17 bits) | dstlocal (8 bits) << 17
__global__ __launch_bounds__(256) void k_bscatter(const int* __restrict__ ei,
                                                  int* __restrict__ bucket_fill,
                                                  unsigned* __restrict__ bpairs) {
    __shared__ int h[NBUCKETS];
    __shared__ int basep[NBUCKETS];
    int t = threadIdx.x;
    const int* dstp = ei + N_EDGES;
    int base = blockIdx.x * CHUNK;

    for (int i = t; i < NBUCKETS; i += 256) h[i] = 0;
    __syncthreads();
    for (int i = t; i < CHUNK; i += 256)
        atomicAdd(&h[dstp[base + i] >> 8], 1);
    __syncthreads();
    for (int i = t; i < NBUCKETS; i += 256) {
        int c = h[i];
        basep[i] = c ? atomicAdd(&bucket_fill[i], c) : 0;
    }
    __syncthreads();
    for (int i = t; i < NBUCKETS; i += 256) h[i] = 0;  // reuse as rank
    __syncthreads();
    for (int i = t; i < CHUNK; i += 256) {
        int d = dstp[base + i];
        int s = ei[base + i];
        int b = d >> 8;
        int r = atomicAdd(&h[b], 1);
        bpairs[basep[b] + r] = (unsigned)s | ((unsigned)(d & 255) << 17);
    }
}

__global__ __launch_bounds__(256) void k_bbuild(const unsigned* __restrict__ bpairs,
                                                const int* __restrict__ bucket_base,
                                                int* __restrict__ row_ptr,
                                                int* __restrict__ cnt,
                                                float* __restrict__ dinv,
                                                int* __restrict__ csr_src) {
    __shared__ int h[256];
    __shared__ int sc[256];
    int b = blockIdx.x;
    int t = threadIdx.x;
    int e0 = bucket_base[b], e1 = bucket_base[b + 1];

    h[t] = 0;
    __syncthreads();
    for (int i = e0 + t; i < e1; i += 256)
        atomicAdd(&h[bpairs[i] >> 17], 1);
    __syncthreads();
    int v = h[t];
    sc[t] = v;
    __syncthreads();
    for (int off = 1; off < 256; off <<= 1) {
        int x = (t >= off) ? sc[t - off] : 0;
        __syncthreads();
        sc[t] += x;
        __syncthreads();
    }
    int ex = sc[t] - v;
    int node = b * 256 + t;
    if (node < N_NODES) {
        cnt[node] = v;
        dinv[node] = rsqrtf((float)(v + 1));
        row_ptr[node] = e0 + ex;
    }
    __syncthreads();
    h[t] = e0 + ex;               // absolute fill cursor
    __syncthreads();
    for (int i = e0 + t; i < e1; i += 256) {
        unsigned p = bpairs[i];
        int pos = atomicAdd(&h[p >> 17], 1);
        csr_src[pos] = (int)(p & 0x1FFFFu);
    }
}

// ------- W repack: fp32 [128x128] -> bf16 hi/lo in MFMA B-fragment order -------
// B-frag (16x16x32): lane = q*16 + n16 holds B[k = ks*32 + q*8 + j][n = c*16 + n16],
// j = 0..7 contiguous. Storage: frag[((l*32 + ks*8 + c)*64 + lane)*8 + j].

__global__ __launch_bounds__(256) void k_wprep(const float* __restrict__ W0,
                                               const float* __restrict__ W1,
                                               const float* __restrict__ W2,
                                               short* __restrict__ fhi,
                                               short* __restrict__ flo) {
    int idx = blockIdx.x * 256 + threadIdx.x;   // 3 * 16384
    int l = idx >> 14, e = idx & 16383;
    const float* W = (l == 0) ? W0 : (l == 1) ? W1 : W2;
    float w = W[e];
    int k = e >> 7, n = e & 127;
    int ks = k >> 5, q = (k >> 3) & 3, j = k & 7;
    int c = n >> 4, n16 = n & 15;
    int lane = q * 16 + n16;
    int dst = ((l * 32 + ks * 8 + c) * 64 + lane) * 8 + j;
    short hi, lo;
    split_bf16(w, hi, lo);
    fhi[dst] = hi;
    flo[dst] = lo;
}

// ------- GEMM: H16 = fp16( (X @ W) * dinv[row] ) via split-bf16 MFMA -------
// Latency-restructured: all 16 A float4 loads hoisted to entry (256B/lane in
// flight), B hi/lo frags staged in LDS (2x32KB) so the MFMA loop is pure
// ds_read_b128 + MFMA. 2 blocks/CU (launch_bounds cap + 64KB LDS).

__global__ __launch_bounds__(256, 2) void k_gemm_mfma(const float* __restrict__ X,
                                                      const short* __restrict__ fhi,
                                                      const short* __restrict__ flo,
                                                      const float* __restrict__ dinv,
                                                      __half* __restrict__ H16,
                                                      int layer) {
    __shared__ short Bh[16384];    // 32 KB
    __shared__ short Bl[16384];    // 32 KB

    int t = threadIdx.x;
    int wave = t >> 6, lane = t & 63;
    int q = lane >> 4, n16 = lane & 15;
    int row_base = blockIdx.x * 128 + wave * 32;

    // hoist all A loads: 2 row-tiles x 4 ks x 32 B  (issued before any use)
    int r0 = row_base + n16;       if (r0 > N_NODES - 1) r0 = N_NODES - 1;
    int r1 = row_base + 16 + n16;  if (r1 > N_NODES - 1) r1 = N_NODES - 1;
    const float* p0 = X + (long long)r0 * 128 + q * 8;
    const float* p1 = X + (long long)r1 * 128 + q * 8;
    float4 a[2][4][2];
#pragma unroll
    for (int ks = 0; ks < 4; ++ks) {
        a[0][ks][0] = *(const float4*)(p0 + ks * 32);
        a[0][ks][1] = *(const float4*)(p0 + ks * 32 + 4);
        a[1][ks][0] = *(const float4*)(p1 + ks * 32);
        a[1][ks][1] = *(const float4*)(p1 + ks * 32 + 4);
    }

    // stage this layer's B frags into LDS (2048 float4 per array)
    {
        const float4* sh_ = (const float4*)(fhi + layer * 16384);
        const float4* sl_ = (const float4*)(flo + layer * 16384);
        float4* dh = (float4*)Bh;
        float4* dl = (float4*)Bl;
#pragma unroll
        for (int i = 0; i < 8; ++i) {
            dh[t + i * 256] = sh_[t + i * 256];
            dl[t + i * 256] = sl_[t + i * 256];
        }
    }

    // split A into bf16 hi/lo fragments (runs under vmcnt shadow)
    sh8 ah[2][4], al[2][4];
#pragma unroll
    for (int r = 0; r < 2; ++r)
#pragma unroll
        for (int ks = 0; ks < 4; ++ks) {
            float xs[8];
            xs[0] = a[r][ks][0].x; xs[1] = a[r][ks][0].y;
            xs[2] = a[r][ks][0].z; xs[3] = a[r][ks][0].w;
            xs[4] = a[r][ks][1].x; xs[5] = a[r][ks][1].y;
            xs[6] = a[r][ks][1].z; xs[7] = a[r][ks][1].w;
#pragma unroll
            for (int j = 0; j < 8; ++j) {
                short h, l;
                split_bf16(xs[j], h, l);
                ah[r][ks][j] = h;
                al[r][ks][j] = l;
            }
        }

    fl4 acc[2][8];
#pragma unroll
    for (int r = 0; r < 2; ++r)
#pragma unroll
        for (int c = 0; c < 8; ++c) acc[r][c] = (fl4){0.f, 0.f, 0.f, 0.f};

    __syncthreads();

    // MFMA loop: pure LDS reads + MFMA
#pragma unroll
    for (int ks = 0; ks < 4; ++ks)
#pragma unroll
        for (int c = 0; c < 8; ++c) {
            sh8 bh = *(const sh8*)&Bh[((ks * 8 + c) * 64 + lane) * 8];
            sh8 bl = *(const sh8*)&Bl[((ks * 8 + c) * 64 + lane) * 8];
#pragma unroll
            for (int r = 0; r < 2; ++r) {
                acc[r][c] = __builtin_amdgcn_mfma_f32_16x16x32_bf16(ah[r][ks], bh, acc[r][c], 0, 0, 0);
                acc[r][c] = __builtin_amdgcn_mfma_f32_16x16x32_bf16(al[r][ks], bh, acc[r][c], 0, 0, 0);
                acc[r][c] = __builtin_amdgcn_mfma_f32_16x16x32_bf16(ah[r][ks], bl, acc[r][c], 0, 0, 0);
            }
        }

    // epilogue: C/D layout row = q*4 + reg, col = c*16 + n16
#pragma unroll
    for (int r = 0; r < 2; ++r)
#pragma unroll
        for (int reg = 0; reg < 4; ++reg) {
            int grow = row_base + r * 16 + q * 4 + reg;
            if (grow < N_NODES) {
                float sc = dinv[grow];
                __half* dst = H16 + (long long)grow * 128 + n16;
#pragma unroll
                for (int c = 0; c < 8; ++c)
                    dst[c * 16] = __float2half(acc[r][c][reg] * sc);
            }
        }
}

// ---------------- gather aggregation + bias + relu ----------------

__global__ __launch_bounds__(256) void k_gather(const __half2* __restrict__ H2,
                                                const int* __restrict__ csr_src,
                                                const int* __restrict__ row_ptr,
                                                const int* __restrict__ cnt,
                                                const float* __restrict__ dinv,
                                                const float* __restrict__ b,
                                                float* __restrict__ out) {
    int node = blockIdx.x * 4 + (threadIdx.x >> 6);
    int lane = threadIdx.x & 63;
    if (node >= N_NODES) return;

    int start = row_ptr[node];
    int n = cnt[node];

    float2 self_ = __half22float2(H2[node * 64 + lane]);
    float accx = self_.x, accy = self_.y;

    int j = 0;
    for (; j + 8 <= n; j += 8) {
        int s[8];
#pragma unroll
        for (int u = 0; u < 8; ++u) s[u] = csr_src[start + j + u];
        float2 h[8];
#pragma unroll
        for (int u = 0; u < 8; ++u) h[u] = __half22float2(H2[s[u] * 64 + lane]);
#pragma unroll
        for (int u = 0; u < 8; ++u) { accx += h[u].x; accy += h[u].y; }
    }
    for (; j < n; ++j) {
        float2 h = __half22float2(H2[csr_src[start + j] * 64 + lane]);
        accx += h.x; accy += h.y;
    }

    float dd = dinv[node];
    float2 bb = ((const float2*)b)[lane];
    float2 v;
    v.x = fmaxf(fmaf(accx, dd, bb.x), 0.0f);
    v.y = fmaxf(fmaf(accy, dd, bb.y), 0.0f);
    ((float2*)out)[node * 64 + lane] = v;
}

// ---------------- launch ----------------

extern "C" void kernel_launch(void* const* d_in, const int* in_sizes, int n_in,
                              void* d_out, int out_size, void* d_ws, size_t ws_size,
                              hipStream_t stream) {
    const float* x  = (const float*)d_in[0];
    const int*   ei = (const int*)d_in[1];   // int32: [0,E)=src, [E,2E)=dst
    const float* Wm[3] = {(const float*)d_in[2], (const float*)d_in[4], (const float*)d_in[6]};
    const float* bv[3] = {(const float*)d_in[3], (const float*)d_in[5], (const float*)d_in[7]};
    float* out = (float*)d_out;

    char* w = (char*)d_ws;
    int*      row_ptr     = (int*)(w + 0);            // 0.4 MB
    int*      cnt         = (int*)(w + 400384);       // 0.4 MB
    float*    dinv        = (float*)(w + 800768);     // 0.4 MB
    int*      bucket_cnt  = (int*)(w + 1201152);      // 2 KB
    int*      bucket_base = (int*)(w + 1203200);      // 2 KB
    int*      bucket_fill = (int*)(w + 1205248);      // 2 KB
    unsigned* bpairs      = (unsigned*)(w + 1207296); // 12.8 MB
    int*      csr_src     = (int*)(w + 14007808);     // 12.8 MB
    short*    fragHi      = (short*)(w + 26808320);   // 96 KB (3 layers)
    short*    fragLo      = (short*)(w + 26906624);   // 96 KB
    __half*   H16         = (__half*)(w + 27004928);  // 25.6 MB (total ~52.6 MB)

    // CSR build via bucketed counting sort + W fragment repack
    k_bzero<<<1, 512, 0, stream>>>(bucket_cnt);
    k_bhist<<<256, 256, 0, stream>>>(ei + N_EDGES, bucket_cnt);
    k_bscan<<<1, 512, 0, stream>>>(bucket_cnt, bucket_base, bucket_fill);
    k_bscatter<<<256, 256, 0, stream>>>(ei, bucket_fill, bpairs);
    k_bbuild<<<NBUCKETS, 256, 0, stream>>>(bpairs, bucket_base, row_ptr, cnt, dinv, csr_src);
    k_wprep<<<192, 256, 0, stream>>>(Wm[0], Wm[1], Wm[2], fragHi, fragLo);

    // 3 GCN layers; d_out doubles as the fp32 ping buffer
    const float* xin = x;
    for (int l = 0; l < 3; ++l) {
        k_gemm_mfma<<<(N_NODES + 127) / 128, 256, 0, stream>>>(xin, fragHi, fragLo,
                                                               dinv, H16, l);
        k_gather<<<(N_NODES + 3) / 4, 256, 0, stream>>>((const __half2*)H16, csr_src,
                                                        row_ptr, cnt, dinv, bv[l], out);
        xin = out;
    }
}

// Round 8
// 624.792 us; speedup vs baseline: 13.5354x; 1.0016x over previous
//
#include <hip/hip_runtime.h>
#include <hip/hip_fp16.h>

#define N_NODES 100000
#define N_EDGES 3200000
#define NBUCKETS 391          // ceil(100000 / 256); bucket = dst >> 8
#define NCHUNKB 512           // blocks for hist/scatter
#define CHUNK 6250            // N_EDGES / NCHUNKB
// FEATURE == HIDDEN == 128
// edge_index arrives as int32: ei[0..E) = src, ei[E..2E) = dst.

typedef __attribute__((ext_vector_type(8))) short sh8;   // 8 bf16 (4 VGPRs)
typedef __attribute__((ext_vector_type(4))) float fl4;   // MFMA acc

// split fp32 into bf16 hi + bf16 lo (both round-to-nearest-even)
__device__ inline void split_bf16(float x, short& hi, short& lo) {
    unsigned u = __float_as_uint(x);
    unsigned r = u + 0x7FFFu + ((u >> 16) & 1u);
    hi = (short)(r >> 16);
    float hif = __uint_as_float(r & 0xFFFF0000u);
    float lof = x - hif;
    unsigned u2 = __float_as_uint(lof);
    lo = (short)((u2 + 0x7FFFu + ((u2 >> 16) & 1u)) >> 16);
}

// ---------------- bucketed CSR build ----------------

__global__ __launch_bounds__(512) void k_bzero(int* __restrict__ bucket_cnt) {
    int t = threadIdx.x;
    if (t < NBUCKETS) bucket_cnt[t] = 0;
}

__global__ __launch_bounds__(256) void k_bhist(const int* __restrict__ ei_dst,
                                               int* __restrict__ bucket_cnt) {
    __shared__ int h[NBUCKETS];
    int t = threadIdx.x;
    for (int i = t; i < NBUCKETS; i += 256) h[i] = 0;
    __syncthreads();
    int base = blockIdx.x * CHUNK;
    for (int i = t; i < CHUNK; i += 256)
        atomicAdd(&h[ei_dst[base + i] >> 8], 1);
    __syncthreads();
    for (int i = t; i < NBUCKETS; i += 256)
        if (h[i]) atomicAdd(&bucket_cnt[i], h[i]);
}

__global__ __launch_bounds__(512) void k_bscan(const int* __restrict__ bucket_cnt,
                                               int* __restrict__ bucket_base,
                                               int* __restrict__ bucket_fill) {
    __shared__ int s[512];
    int t = threadIdx.x;
    int v = (t < NBUCKETS) ? bucket_cnt[t] : 0;
    s[t] = v;
    __syncthreads();
    for (int off = 1; off < 512; off <<= 1) {
        int x = (t >= off) ? s[t - off] : 0;
        __syncthreads();
        s[t] += x;
        __syncthreads();
    }
    int ex = s[t] - v;
    if (t < NBUCKETS) { bucket_base[t] = ex; bucket_fill[t] = ex; }
    if (t == NBUCKETS - 1) bucket_base[NBUCKETS] = s[t];
}

// packed entry: src (17 bits) | dstlocal (8 bits) << 17
__global__ __launch_bounds__(256) void k_bscatter(const int* __restrict__ ei,
                                                  int* __restrict__ bucket_fill,
                                                  unsigned* __restrict__ bpairs) {
    __shared__ int h[NBUCKETS];
    __shared__ int basep[NBUCKETS];
    int t = threadIdx.x;
    const int* dstp = ei + N_EDGES;
    int base = blockIdx.x * CHUNK;

    for (int i = t; i < NBUCKETS; i += 256) h[i] = 0;
    __syncthreads();
    for (int i = t; i < CHUNK; i += 256)
        atomicAdd(&h[dstp[base + i] >> 8], 1);
    __syncthreads();
    for (int i = t; i < NBUCKETS; i += 256) {
        int c = h[i];
        basep[i] = c ? atomicAdd(&bucket_fill[i], c) : 0;
    }
    __syncthreads();
    for (int i = t; i < NBUCKETS; i += 256) h[i] = 0;  // reuse as rank
    __syncthreads();
    for (int i = t; i < CHUNK; i += 256) {
        int d = dstp[base + i];
        int s = ei[base + i];
        int b = d >> 8;
        int r = atomicAdd(&h[b], 1);
        bpairs[basep[b] + r] = (unsigned)s | ((unsigned)(d & 255) << 17);
    }
}

__global__ __launch_bounds__(256) void k_bbuild(const unsigned* __restrict__ bpairs,
                                                const int* __restrict__ bucket_base,
                                                int* __restrict__ row_ptr,
                                                int* __restrict__ cnt,
                                                float* __restrict__ dinv,
                                                int* __restrict__ csr_src) {
    __shared__ int h[256];
    __shared__ int sc[256];
    int b = blockIdx.x;
    int t = threadIdx.x;
    int e0 = bucket_base[b], e1 = bucket_base[b + 1];

    h[t] = 0;
    __syncthreads();
    for (int i = e0 + t; i < e1; i += 256)
        atomicAdd(&h[bpairs[i] >> 17], 1);
    __syncthreads();
    int v = h[t];
    sc[t] = v;
    __syncthreads();
    for (int off = 1; off < 256; off <<= 1) {
        int x = (t >= off) ? sc[t - off] : 0;
        __syncthreads();
        sc[t] += x;
        __syncthreads();
    }
    int ex = sc[t] - v;
    int node = b * 256 + t;
    if (node < N_NODES) {
        cnt[node] = v;
        dinv[node] = rsqrtf((float)(v + 1));
        row_ptr[node] = e0 + ex;
    }
    __syncthreads();
    h[t] = e0 + ex;               // absolute fill cursor
    __syncthreads();
    for (int i = e0 + t; i < e1; i += 256) {
        unsigned p = bpairs[i];
        int pos = atomicAdd(&h[p >> 17], 1);
        csr_src[pos] = (int)(p & 0x1FFFFu);
    }
}

// ------- W repack: fp32 [128x128] -> bf16 hi/lo in MFMA B-fragment order -------
// B-frag (16x16x32): lane = q*16 + n16 holds B[k = ks*32 + q*8 + j][n = c*16 + n16],
// j = 0..7 contiguous. Storage: frag[((l*32 + ks*8 + c)*64 + lane)*8 + j].

__global__ __launch_bounds__(256) void k_wprep(const float* __restrict__ W0,
                                               const float* __restrict__ W1,
                                               const float* __restrict__ W2,
                                               short* __restrict__ fhi,
                                               short* __restrict__ flo) {
    int idx = blockIdx.x * 256 + threadIdx.x;   // 3 * 16384
    int l = idx >> 14, e = idx & 16383;
    const float* W = (l == 0) ? W0 : (l == 1) ? W1 : W2;
    float w = W[e];
    int k = e >> 7, n = e & 127;
    int ks = k >> 5, q = (k >> 3) & 3, j = k & 7;
    int c = n >> 4, n16 = n & 15;
    int lane = q * 16 + n16;
    int dst = ((l * 32 + ks * 8 + c) * 64 + lane) * 8 + j;
    short hi, lo;
    split_bf16(w, hi, lo);
    fhi[dst] = hi;
    flo[dst] = lo;
}

// ------- GEMM v3: H16 = fp16( (X @ W) * dinv[row] ) via split-bf16 MFMA -------
// No LDS, no barriers. 1 row-tile (16 rows) per wave, 4 waves/block.
// A fully hoisted; B frags batch-loaded from L2 per ks (16 dwordx4 in flight).

__global__ __launch_bounds__(256, 3) void k_gemm_mfma(const float* __restrict__ X,
                                                      const short* __restrict__ fhi,
                                                      const short* __restrict__ flo,
                                                      const float* __restrict__ dinv,
                                                      __half* __restrict__ H16) {
    int t = threadIdx.x;
    int wave = t >> 6, lane = t & 63;
    int q = lane >> 4, n16 = lane & 15;
    int tile = blockIdx.x * 4 + wave;          // 16-row tile id
    int row_base = tile * 16;

    // hoist all A loads: 4 ks x 32 B per lane
    int r0 = row_base + n16;
    if (r0 > N_NODES - 1) r0 = N_NODES - 1;
    const float* p0 = X + (long long)r0 * 128 + q * 8;
    float4 a[4][2];
#pragma unroll
    for (int ks = 0; ks < 4; ++ks) {
        a[ks][0] = *(const float4*)(p0 + ks * 32);
        a[ks][1] = *(const float4*)(p0 + ks * 32 + 4);
    }

    // split A into bf16 hi/lo fragments (under vmcnt shadow)
    sh8 ah[4], al[4];
#pragma unroll
    for (int ks = 0; ks < 4; ++ks) {
        float xs[8];
        xs[0] = a[ks][0].x; xs[1] = a[ks][0].y; xs[2] = a[ks][0].z; xs[3] = a[ks][0].w;
        xs[4] = a[ks][1].x; xs[5] = a[ks][1].y; xs[6] = a[ks][1].z; xs[7] = a[ks][1].w;
#pragma unroll
        for (int j = 0; j < 8; ++j) {
            short h, l;
            split_bf16(xs[j], h, l);
            ah[ks][j] = h;
            al[ks][j] = l;
        }
    }

    const sh8* __restrict__ BH = (const sh8*)fhi;
    const sh8* __restrict__ BL = (const sh8*)flo;

    fl4 acc[8];
#pragma unroll
    for (int c = 0; c < 8; ++c) acc[c] = (fl4){0.f, 0.f, 0.f, 0.f};

#pragma unroll
    for (int ks = 0; ks < 4; ++ks) {
        // batch-load all 16 B frags for this ks (independent, go in flight together)
        sh8 bh[8], bl[8];
#pragma unroll
        for (int c = 0; c < 8; ++c) {
            bh[c] = BH[(ks * 8 + c) * 64 + lane];
            bl[c] = BL[(ks * 8 + c) * 64 + lane];
        }
#pragma unroll
        for (int c = 0; c < 8; ++c) {
            acc[c] = __builtin_amdgcn_mfma_f32_16x16x32_bf16(ah[ks], bh[c], acc[c], 0, 0, 0);
            acc[c] = __builtin_amdgcn_mfma_f32_16x16x32_bf16(al[ks], bh[c], acc[c], 0, 0, 0);
            acc[c] = __builtin_amdgcn_mfma_f32_16x16x32_bf16(ah[ks], bl[c], acc[c], 0, 0, 0);
        }
    }

    // epilogue: C/D layout row = q*4 + reg, col = c*16 + n16
#pragma unroll
    for (int reg = 0; reg < 4; ++reg) {
        int grow = row_base + q * 4 + reg;
        if (grow < N_NODES) {
            float sc = dinv[grow];
            __half* dst = H16 + (long long)grow * 128 + n16;
#pragma unroll
            for (int c = 0; c < 8; ++c)
                dst[c * 16] = __float2half(acc[c][reg] * sc);
        }
    }
}

// ---------------- gather aggregation + bias + relu ----------------
// wave-uniform node id (readfirstlane) so index loads can take the scalar path

__global__ __launch_bounds__(256) void k_gather(const __half2* __restrict__ H2,
                                                const int* __restrict__ csr_src,
                                                const int* __restrict__ row_ptr,
                                                const int* __restrict__ cnt,
                                                const float* __restrict__ dinv,
                                                const float* __restrict__ b,
                                                float* __restrict__ out) {
    int wv = __builtin_amdgcn_readfirstlane(threadIdx.x >> 6);
    int node = blockIdx.x * 4 + wv;
    int lane = threadIdx.x & 63;
    if (node >= N_NODES) return;

    int start = row_ptr[node];
    int n = cnt[node];

    float2 self_ = __half22float2(H2[node * 64 + lane]);
    float accx = self_.x, accy = self_.y;

    int j = 0;
    for (; j + 8 <= n; j += 8) {
        int s[8];
#pragma unroll
        for (int u = 0; u < 8; ++u) s[u] = csr_src[start + j + u];
        float2 h[8];
#pragma unroll
        for (int u = 0; u < 8; ++u) h[u] = __half22float2(H2[s[u] * 64 + lane]);
#pragma unroll
        for (int u = 0; u < 8; ++u) { accx += h[u].x; accy += h[u].y; }
    }
    for (; j < n; ++j) {
        float2 h = __half22float2(H2[csr_src[start + j] * 64 + lane]);
        accx += h.x; accy += h.y;
    }

    float dd = dinv[node];
    float2 bb = ((const float2*)b)[lane];
    float2 v;
    v.x = fmaxf(fmaf(accx, dd, bb.x), 0.0f);
    v.y = fmaxf(fmaf(accy, dd, bb.y), 0.0f);
    ((float2*)out)[node * 64 + lane] = v;
}

// ---------------- launch ----------------

extern "C" void kernel_launch(void* const* d_in, const int* in_sizes, int n_in,
                              void* d_out, int out_size, void* d_ws, size_t ws_size,
                              hipStream_t stream) {
    const float* x  = (const float*)d_in[0];
    const int*   ei = (const int*)d_in[1];   // int32: [0,E)=src, [E,2E)=dst
    const float* Wm[3] = {(const float*)d_in[2], (const float*)d_in[4], (const float*)d_in[6]};
    const float* bv[3] = {(const float*)d_in[3], (const float*)d_in[5], (const float*)d_in[7]};
    float* out = (float*)d_out;

    char* w = (char*)d_ws;
    int*      row_ptr     = (int*)(w + 0);            // 0.4 MB
    int*      cnt         = (int*)(w + 400384);       // 0.4 MB
    float*    dinv        = (float*)(w + 800768);     // 0.4 MB
    int*      bucket_cnt  = (int*)(w + 1201152);      // 2 KB
    int*      bucket_base = (int*)(w + 1203200);      // 2 KB
    int*      bucket_fill = (int*)(w + 1205248);      // 2 KB
    unsigned* bpairs      = (unsigned*)(w + 1207296); // 12.8 MB
    int*      csr_src     = (int*)(w + 14007808);     // 12.8 MB
    short*    fragHi      = (short*)(w + 26808320);   // 96 KB (3 layers)
    short*    fragLo      = (short*)(w + 26906624);   // 96 KB
    __half*   H16         = (__half*)(w + 27004928);  // 25.6 MB (total ~52.6 MB)

    // CSR build via bucketed counting sort + W fragment repack
    k_bzero<<<1, 512, 0, stream>>>(bucket_cnt);
    k_bhist<<<NCHUNKB, 256, 0, stream>>>(ei + N_EDGES, bucket_cnt);
    k_bscan<<<1, 512, 0, stream>>>(bucket_cnt, bucket_base, bucket_fill);
    k_bscatter<<<NCHUNKB, 256, 0, stream>>>(ei, bucket_fill, bpairs);
    k_bbuild<<<NBUCKETS, 256, 0, stream>>>(bpairs, bucket_base, row_ptr, cnt, dinv, csr_src);
    k_wprep<<<192, 256, 0, stream>>>(Wm[0], Wm[1], Wm[2], fragHi, fragLo);

    // 3 GCN layers; d_out doubles as the fp32 ping buffer
    const float* xin = x;
    for (int l = 0; l < 3; ++l) {
        k_gemm_mfma<<<1563, 256, 0, stream>>>(xin, fragHi + l * 16384, fragLo + l * 16384,
                                              dinv, H16);
        k_gather<<<(N_NODES + 3) / 4, 256, 0, stream>>>((const __half2*)H16, csr_src,
                                                        row_ptr, cnt, dinv, bv[l], out);
        xin = out;
    }
}

// Round 9
// 594.064 us; speedup vs baseline: 14.2355x; 1.0517x over previous
//
#include <hip/hip_runtime.h>
#include <hip/hip_fp16.h>

#define N_NODES 100000
#define N_EDGES 3200000
#define NBUCKETS 391          // ceil(100000 / 256); bucket = dst >> 8
#define NCHUNKB 256           // blocks for hist/scatter
#define CHUNK 12500           // N_EDGES / NCHUNKB
// FEATURE == HIDDEN == 128
// edge_index arrives as int32: ei[0..E) = src, ei[E..2E) = dst.

typedef __attribute__((ext_vector_type(8))) short sh8;   // 8 bf16 (4 VGPRs)
typedef __attribute__((ext_vector_type(4))) float fl4;   // MFMA acc

// split fp32 into bf16 hi + bf16 lo (both round-to-nearest-even)
__device__ inline void split_bf16(float x, short& hi, short& lo) {
    unsigned u = __float_as_uint(x);
    unsigned r = u + 0x7FFFu + ((u >> 16) & 1u);
    hi = (short)(r >> 16);
    float hif = __uint_as_float(r & 0xFFFF0000u);
    float lof = x - hif;
    unsigned u2 = __float_as_uint(lof);
    lo = (short)((u2 + 0x7FFFu + ((u2 >> 16) & 1u)) >> 16);
}

// ---------------- bucketed CSR build ----------------

__global__ __launch_bounds__(256) void k_bhist(const int* __restrict__ ei_dst,
                                               int* __restrict__ bucket_cnt) {
    __shared__ int h[NBUCKETS];
    int t = threadIdx.x;
    for (int i = t; i < NBUCKETS; i += 256) h[i] = 0;
    __syncthreads();
    int base = blockIdx.x * CHUNK;
    for (int i = t; i < CHUNK; i += 256)
        atomicAdd(&h[ei_dst[base + i] >> 8], 1);
    __syncthreads();
    for (int i = t; i < NBUCKETS; i += 256)
        if (h[i]) atomicAdd(&bucket_cnt[i], h[i]);
}

__global__ __launch_bounds__(512) void k_bscan(const int* __restrict__ bucket_cnt,
                                               int* __restrict__ bucket_base,
                                               int* __restrict__ bucket_fill) {
    __shared__ int s[512];
    int t = threadIdx.x;
    int v = (t < NBUCKETS) ? bucket_cnt[t] : 0;
    s[t] = v;
    __syncthreads();
    for (int off = 1; off < 512; off <<= 1) {
        int x = (t >= off) ? s[t - off] : 0;
        __syncthreads();
        s[t] += x;
        __syncthreads();
    }
    int ex = s[t] - v;
    if (t < NBUCKETS) { bucket_base[t] = ex; bucket_fill[t] = ex; }
    if (t == NBUCKETS - 1) bucket_base[NBUCKETS] = s[t];
}

// packed entry: src (17 bits) | dstlocal (8 bits) << 17
__global__ __launch_bounds__(256) void k_bscatter(const int* __restrict__ ei,
                                                  int* __restrict__ bucket_fill,
                                                  unsigned* __restrict__ bpairs) {
    __shared__ int h[NBUCKETS];
    __shared__ int basep[NBUCKETS];
    int t = threadIdx.x;
    const int* dstp = ei + N_EDGES;
    int base = blockIdx.x * CHUNK;

    for (int i = t; i < NBUCKETS; i += 256) h[i] = 0;
    __syncthreads();
    for (int i = t; i < CHUNK; i += 256)
        atomicAdd(&h[dstp[base + i] >> 8], 1);
    __syncthreads();
    for (int i = t; i < NBUCKETS; i += 256) {
        int c = h[i];
        basep[i] = c ? atomicAdd(&bucket_fill[i], c) : 0;
    }
    __syncthreads();
    for (int i = t; i < NBUCKETS; i += 256) h[i] = 0;  // reuse as rank
    __syncthreads();
    for (int i = t; i < CHUNK; i += 256) {
        int d = dstp[base + i];
        int s = ei[base + i];
        int b = d >> 8;
        int r = atomicAdd(&h[b], 1);
        bpairs[basep[b] + r] = (unsigned)s | ((unsigned)(d & 255) << 17);
    }
}

__global__ __launch_bounds__(256) void k_bbuild(const unsigned* __restrict__ bpairs,
                                                const int* __restrict__ bucket_base,
                                                int* __restrict__ row_ptr,
                                                int* __restrict__ cnt,
                                                float* __restrict__ dinv,
                                                int* __restrict__ csr_src) {
    __shared__ int h[256];
    __shared__ int sc[256];
    int b = blockIdx.x;
    int t = threadIdx.x;
    int e0 = bucket_base[b], e1 = bucket_base[b + 1];

    h[t] = 0;
    __syncthreads();
    for (int i = e0 + t; i < e1; i += 256)
        atomicAdd(&h[bpairs[i] >> 17], 1);
    __syncthreads();
    int v = h[t];
    sc[t] = v;
    __syncthreads();
    for (int off = 1; off < 256; off <<= 1) {
        int x = (t >= off) ? sc[t - off] : 0;
        __syncthreads();
        sc[t] += x;
        __syncthreads();
    }
    int ex = sc[t] - v;
    int node = b * 256 + t;
    if (node < N_NODES) {
        cnt[node] = v;
        dinv[node] = rsqrtf((float)(v + 1));
        row_ptr[node] = e0 + ex;
    }
    __syncthreads();
    h[t] = e0 + ex;               // absolute fill cursor
    __syncthreads();
    for (int i = e0 + t; i < e1; i += 256) {
        unsigned p = bpairs[i];
        int pos = atomicAdd(&h[p >> 17], 1);
        csr_src[pos] = (int)(p & 0x1FFFFu);
    }
}

// ------- W repack (+ fused bucket_cnt zero in the extra block) -------
// B-frag (16x16x32): lane = q*16 + n16 holds B[k = ks*32 + q*8 + j][n = c*16 + n16],
// j = 0..7 contiguous. Storage: frag[((l*32 + ks*8 + c)*64 + lane)*8 + j].

__global__ __launch_bounds__(256) void k_wprep(const float* __restrict__ W0,
                                               const float* __restrict__ W1,
                                               const float* __restrict__ W2,
                                               short* __restrict__ fhi,
                                               short* __restrict__ flo,
                                               int* __restrict__ bucket_cnt) {
    if (blockIdx.x == 192) {   // fused: zero the bucket counters
        for (int i = threadIdx.x; i < NBUCKETS; i += 256) bucket_cnt[i] = 0;
        return;
    }
    int idx = blockIdx.x * 256 + threadIdx.x;   // 3 * 16384
    int l = idx >> 14, e = idx & 16383;
    const float* W = (l == 0) ? W0 : (l == 1) ? W1 : W2;
    float w = W[e];
    int k = e >> 7, n = e & 127;
    int ks = k >> 5, q = (k >> 3) & 3, j = k & 7;
    int c = n >> 4, n16 = n & 15;
    int lane = q * 16 + n16;
    int dst = ((l * 32 + ks * 8 + c) * 64 + lane) * 8 + j;
    short hi, lo;
    split_bf16(w, hi, lo);
    fhi[dst] = hi;
    flo[dst] = lo;
}

// ------- GEMM v4: H16 = fp16( (X @ W) * dinv[row] ) via split-bf16 MFMA -------
// 512 threads = 8 waves, 1 row-tile (16 rows) per wave -> 128 rows/block.
// B hi/lo staged in 64 KB LDS; MFMA loop = 2x ds_read_b128 + 3 MFMA (m97 pattern).
// launch_bounds(512,4) caps VGPR at 128 -> 2 blocks/CU = 16 waves/CU, 128 KB LDS/CU.

__global__ __launch_bounds__(512, 4) void k_gemm_mfma(const float* __restrict__ X,
                                                      const short* __restrict__ fhi,
                                                      const short* __restrict__ flo,
                                                      const float* __restrict__ dinv,
                                                      __half* __restrict__ H16) {
    __shared__ short Bh[16384];    // 32 KB
    __shared__ short Bl[16384];    // 32 KB

    int t = threadIdx.x;
    int wave = t >> 6, lane = t & 63;
    int q = lane >> 4, n16 = lane & 15;
    int row_base = blockIdx.x * 128 + wave * 16;

    // hoist all A loads: 4 ks x 32 B per lane (in flight before any use)
    int r0 = row_base + n16;
    if (r0 > N_NODES - 1) r0 = N_NODES - 1;
    const float* p0 = X + (long long)r0 * 128 + q * 8;
    float4 a[4][2];
#pragma unroll
    for (int ks = 0; ks < 4; ++ks) {
        a[ks][0] = *(const float4*)(p0 + ks * 32);
        a[ks][1] = *(const float4*)(p0 + ks * 32 + 4);
    }

    // stage B frags into LDS: 2048 float4 per array, 512 threads -> 4 iters
    {
        const float4* sh_ = (const float4*)fhi;
        const float4* sl_ = (const float4*)flo;
        float4* dh = (float4*)Bh;
        float4* dl = (float4*)Bl;
#pragma unroll
        for (int i = 0; i < 4; ++i) {
            dh[t + i * 512] = sh_[t + i * 512];
            dl[t + i * 512] = sl_[t + i * 512];
        }
    }

    // split A into bf16 hi/lo fragments (under vmcnt shadow)
    sh8 ah[4], al[4];
#pragma unroll
    for (int ks = 0; ks < 4; ++ks) {
        float xs[8];
        xs[0] = a[ks][0].x; xs[1] = a[ks][0].y; xs[2] = a[ks][0].z; xs[3] = a[ks][0].w;
        xs[4] = a[ks][1].x; xs[5] = a[ks][1].y; xs[6] = a[ks][1].z; xs[7] = a[ks][1].w;
#pragma unroll
        for (int j = 0; j < 8; ++j) {
            short h, l;
            split_bf16(xs[j], h, l);
            ah[ks][j] = h;
            al[ks][j] = l;
        }
    }

    fl4 acc[8];
#pragma unroll
    for (int c = 0; c < 8; ++c) acc[c] = (fl4){0.f, 0.f, 0.f, 0.f};

    __syncthreads();

    // MFMA loop: pure LDS reads + MFMA (compiler pipelines via lgkmcnt)
#pragma unroll
    for (int ks = 0; ks < 4; ++ks)
#pragma unroll
        for (int c = 0; c < 8; ++c) {
            sh8 bh = *(const sh8*)&Bh[((ks * 8 + c) * 64 + lane) * 8];
            sh8 bl = *(const sh8*)&Bl[((ks * 8 + c) * 64 + lane) * 8];
            acc[c] = __builtin_amdgcn_mfma_f32_16x16x32_bf16(ah[ks], bh, acc[c], 0, 0, 0);
            acc[c] = __builtin_amdgcn_mfma_f32_16x16x32_bf16(al[ks], bh, acc[c], 0, 0, 0);
            acc[c] = __builtin_amdgcn_mfma_f32_16x16x32_bf16(ah[ks], bl, acc[c], 0, 0, 0);
        }

    // epilogue: C/D layout row = q*4 + reg, col = c*16 + n16
#pragma unroll
    for (int reg = 0; reg < 4; ++reg) {
        int grow = row_base + q * 4 + reg;
        if (grow < N_NODES) {
            float sc = dinv[grow];
            __half* dst = H16 + (long long)grow * 128 + n16;
#pragma unroll
            for (int c = 0; c < 8; ++c)
                dst[c * 16] = __float2half(acc[c][reg] * sc);
        }
    }
}

// ---------------- gather aggregation + bias + relu ----------------
// wave-uniform node id (readfirstlane) so index loads take the scalar path

__global__ __launch_bounds__(256) void k_gather(const __half2* __restrict__ H2,
                                                const int* __restrict__ csr_src,
                                                const int* __restrict__ row_ptr,
                                                const int* __restrict__ cnt,
                                                const float* __restrict__ dinv,
                                                const float* __restrict__ b,
                                                float* __restrict__ out) {
    int wv = __builtin_amdgcn_readfirstlane(threadIdx.x >> 6);
    int node = blockIdx.x * 4 + wv;
    int lane = threadIdx.x & 63;
    if (node >= N_NODES) return;

    int start = row_ptr[node];
    int n = cnt[node];

    float2 self_ = __half22float2(H2[node * 64 + lane]);
    float accx = self_.x, accy = self_.y;

    int j = 0;
    for (; j + 8 <= n; j += 8) {
        int s[8];
#pragma unroll
        for (int u = 0; u < 8; ++u) s[u] = csr_src[start + j + u];
        float2 h[8];
#pragma unroll
        for (int u = 0; u < 8; ++u) h[u] = __half22float2(H2[s[u] * 64 + lane]);
#pragma unroll
        for (int u = 0; u < 8; ++u) { accx += h[u].x; accy += h[u].y; }
    }
    for (; j < n; ++j) {
        float2 h = __half22float2(H2[csr_src[start + j] * 64 + lane]);
        accx += h.x; accy += h.y;
    }

    float dd = dinv[node];
    float2 bb = ((const float2*)b)[lane];
    float2 v;
    v.x = fmaxf(fmaf(accx, dd, bb.x), 0.0f);
    v.y = fmaxf(fmaf(accy, dd, bb.y), 0.0f);
    ((float2*)out)[node * 64 + lane] = v;
}

// ---------------- launch ----------------

extern "C" void kernel_launch(void* const* d_in, const int* in_sizes, int n_in,
                              void* d_out, int out_size, void* d_ws, size_t ws_size,
                              hipStream_t stream) {
    const float* x  = (const float*)d_in[0];
    const int*   ei = (const int*)d_in[1];   // int32: [0,E)=src, [E,2E)=dst
    const float* Wm[3] = {(const float*)d_in[2], (const float*)d_in[4], (const float*)d_in[6]};
    const float* bv[3] = {(const float*)d_in[3], (const float*)d_in[5], (const float*)d_in[7]};
    float* out = (float*)d_out;

    char* w = (char*)d_ws;
    int*      row_ptr     = (int*)(w + 0);            // 0.4 MB
    int*      cnt         = (int*)(w + 400384);       // 0.4 MB
    float*    dinv        = (float*)(w + 800768);     // 0.4 MB
    int*      bucket_cnt  = (int*)(w + 1201152);      // 2 KB
    int*      bucket_base = (int*)(w + 1203200);      // 2 KB
    int*      bucket_fill = (int*)(w + 1205248);      // 2 KB
    unsigned* bpairs      = (unsigned*)(w + 1207296); // 12.8 MB
    int*      csr_src     = (int*)(w + 14007808);     // 12.8 MB
    short*    fragHi      = (short*)(w + 26808320);   // 96 KB (3 layers)
    short*    fragLo      = (short*)(w + 26906624);   // 96 KB
    __half*   H16         = (__half*)(w + 27004928);  // 25.6 MB (total ~52.6 MB)

    // W repack (+ fused bucket zero), then bucketed counting-sort CSR build
    k_wprep<<<193, 256, 0, stream>>>(Wm[0], Wm[1], Wm[2], fragHi, fragLo, bucket_cnt);
    k_bhist<<<NCHUNKB, 256, 0, stream>>>(ei + N_EDGES, bucket_cnt);
    k_bscan<<<1, 512, 0, stream>>>(bucket_cnt, bucket_base, bucket_fill);
    k_bscatter<<<NCHUNKB, 256, 0, stream>>>(ei, bucket_fill, bpairs);
    k_bbuild<<<NBUCKETS, 256, 0, stream>>>(bpairs, bucket_base, row_ptr, cnt, dinv, csr_src);

    // 3 GCN layers; d_out doubles as the fp32 ping buffer
    const float* xin = x;
    for (int l = 0; l < 3; ++l) {
        k_gemm_mfma<<<(N_NODES + 127) / 128, 512, 0, stream>>>(xin, fragHi + l * 16384,
                                                               fragLo + l * 16384, dinv, H16);
        k_gather<<<(N_NODES + 3) / 4, 256, 0, stream>>>((const __half2*)H16, csr_src,
                                                        row_ptr, cnt, dinv, bv[l], out);
        xin = out;
    }
}